// Round 7
// baseline (400.792 us; speedup 1.0000x reference)
//
#include <hip/hip_runtime.h>

#define NTILES_X 65          // ceil(1026/16)
#define NTILES   (65*65)     // 4225
#define OHW      1026

typedef unsigned int  uint;
typedef unsigned short ushort;
typedef float  floatx16 __attribute__((ext_vector_type(16)));
typedef __bf16 bf16x8   __attribute__((ext_vector_type(8)));

__device__ __forceinline__ uint pk2f(float a, float b) {
    ushort lo = __builtin_bit_cast(ushort, (__bf16)a);
    ushort hi = __builtin_bit_cast(ushort, (__bf16)b);
    return (uint)lo | ((uint)hi << 16);
}
__device__ __forceinline__ bf16x8 frag_of(uint a, uint b, uint c, uint d) {
    uint4 u = make_uint4(a, b, c, d);
    return __builtin_bit_cast(bf16x8, u);
}
// k -> element offset in sInB[3][18][18]  (k = ic*9 + ky*3 + kx)
__device__ __forceinline__ constexpr int koff_of(int k) {
    return (k / 9) * 324 + ((k % 9) / 3) * 18 + (k % 3);
}
// one B-frag u16: slot k = (h ? kb : ka); ka,kb compile-time (kb = ka+8).
// k==27 is the bias slot (B=1.0); k>27 -> 0.
__device__ __forceinline__ uint bslot(const ushort* sInB, int base, int h, int ka, int kb) {
    if (kb < 27) {
        int off = h ? koff_of(kb) : koff_of(ka);
        return (uint)sInB[base + off];
    } else if (ka < 27) {
        uint cst = (kb == 27) ? 0x3F80u : 0u;
        uint rd  = (uint)sInB[base + koff_of(ka)];
        return h ? cst : rd;
    } else {
        uint ca = (ka == 27) ? 0x3F80u : 0u;
        uint cb = (kb == 27) ? 0x3F80u : 0u;
        return h ? cb : ca;
    }
}

// ---------------------------------------------------------------------------
// Kernel 1: conv1 (3->32, k3, pad2) via implicit-GEMM MFMA + MFMA bf16 gram.
// (unchanged from R6 — proven at ~45 us / pass)
// ---------------------------------------------------------------------------
__global__ __launch_bounds__(256, 4) void k_conv_gram(
    const float* __restrict__ x,   // [3][1024][1024]
    const float* __restrict__ w1,  // [32][3][3][3]
    const float* __restrict__ b1,  // [32]
    float* __restrict__ partial,   // [nblk][1024]
    int nblk)
{
    __shared__ __align__(16) ushort sInB[3*18*18];   // 1.9 KB bf16 input tile
    __shared__ __align__(16) ushort sFb[256*32];     // 16 KB bf16 F; aliased for reduce

    const int t    = threadIdx.x;
    const int wv   = t >> 6;
    const int lane = t & 63;
    const int h    = lane >> 5;
    const int c    = lane & 31;
    const int c4   = c >> 2, c3 = c & 3;

    // ---- weight(+bias) fragments, built once ----
    const float b1c = b1[c];
    uint wu0[4], wu1[4];
#pragma unroll
    for (int q = 0; q < 4; ++q) {
        {
            int k0 = h * 8 + 2 * q;
            wu0[q] = pk2f(w1[c * 27 + k0], w1[c * 27 + k0 + 1]);
        }
        {
            int k0 = 16 + h * 8 + 2 * q, k1 = k0 + 1;
            float r0 = w1[c * 27 + (k0 < 27 ? k0 : 26)];
            float r1 = w1[c * 27 + (k1 < 27 ? k1 : 26)];
            float v0 = (k0 < 27) ? r0 : (k0 == 27 ? b1c : 0.f);
            float v1 = (k1 < 27) ? r1 : (k1 == 27 ? b1c : 0.f);
            wu1[q] = pk2f(v0, v1);
        }
    }

    floatx16 gacc;
#pragma unroll
    for (int i = 0; i < 16; ++i) gacc[i] = 0.f;

    for (int tile = blockIdx.x; tile < NTILES; tile += nblk) {
        const int ty = tile / NTILES_X;
        const int tx = tile - ty * NTILES_X;
        const int by = ty * 16, bx = tx * 16;
        const bool interior = (ty >= 1) & (ty <= 62) & (tx >= 1) & (tx <= 62);

        __syncthreads();
        if (interior) {
            for (int i = t; i < 972; i += 256) {
                int ic = i / 324, rem = i - ic * 324, r = rem / 18, cc = rem - r * 18;
                float v = x[ic * 1048576 + (by - 2 + r) * 1024 + (bx - 2 + cc)];
                sInB[i] = __builtin_bit_cast(ushort, (__bf16)v);
            }
        } else {
            for (int i = t; i < 972; i += 256) {
                int ic = i / 324, rem = i - ic * 324, r = rem / 18, cc = rem - r * 18;
                int iy = by - 2 + r, ix = bx - 2 + cc;
                float v = 0.f;
                if ((unsigned)iy < 1024u && (unsigned)ix < 1024u)
                    v = x[ic * 1048576 + iy * 1024 + ix];
                sInB[i] = __builtin_bit_cast(ushort, (__bf16)v);
            }
        }
        __syncthreads();

#pragma unroll
        for (int e = 0; e < 2; ++e) {
            const int cb   = 2 * wv + e;
            const int px   = cb * 32 + c;
            const int base = (cb * 2 + (c >> 4)) * 18 + (c & 15);

            floatx16 cacc;
#pragma unroll
            for (int i = 0; i < 16; ++i) cacc[i] = 0.f;

            uint bu[4];
#pragma unroll
            for (int q = 0; q < 4; ++q) {
                uint lo = bslot(sInB, base, h, 2*q,     2*q + 8);
                uint hi = bslot(sInB, base, h, 2*q + 1, 2*q + 9);
                bu[q] = lo | (hi << 16);
            }
            cacc = __builtin_amdgcn_mfma_f32_32x32x16_bf16(
                frag_of(wu0[0], wu0[1], wu0[2], wu0[3]),
                frag_of(bu[0], bu[1], bu[2], bu[3]), cacc, 0, 0, 0);
#pragma unroll
            for (int q = 0; q < 4; ++q) {
                uint lo = bslot(sInB, base, h, 16 + 2*q,     16 + 2*q + 8);
                uint hi = bslot(sInB, base, h, 16 + 2*q + 1, 16 + 2*q + 9);
                bu[q] = lo | (hi << 16);
            }
            cacc = __builtin_amdgcn_mfma_f32_32x32x16_bf16(
                frag_of(wu1[0], wu1[1], wu1[2], wu1[3]),
                frag_of(bu[0], bu[1], bu[2], bu[3]), cacc, 0, 0, 0);

            const int py = px >> 4, pxx = px & 15;
            const uint vmask = ((by + py) < OHW && (bx + pxx) < OHW) ? 0xFFFFFFFFu : 0u;
#pragma unroll
            for (int q = 0; q < 4; ++q) {
                uint u0 = pk2f(cacc[4*q + 0], cacc[4*q + 1]) & vmask;
                uint u1 = pk2f(cacc[4*q + 2], cacc[4*q + 3]) & vmask;
                *(uint2*)&sFb[px * 32 + (((2*q + h) ^ (px & 7)) << 2)] = make_uint2(u0, u1);
            }
        }

#pragma unroll
        for (int s4 = 0; s4 < 4; ++s4) {
            const int pxg = wv * 64 + 16 * s4 + 8 * h;
            uint gu[4];
#pragma unroll
            for (int q = 0; q < 4; ++q) {
                const int j0 = 2 * q, j1 = 2 * q + 1;
                uint lo = sFb[(pxg + j0) * 32 + ((c4 ^ j0) << 2) + c3];
                uint hi = sFb[(pxg + j1) * 32 + ((c4 ^ j1) << 2) + c3];
                gu[q] = lo | (hi << 16);
            }
            bf16x8 gf = frag_of(gu[0], gu[1], gu[2], gu[3]);
            gacc = __builtin_amdgcn_mfma_f32_32x32x16_bf16(gf, gf, gacc, 0, 0, 0);
        }
    }

    __syncthreads();
    {
        float* gp = (float*)sFb;
#pragma unroll
        for (int r = 0; r < 16; ++r) {
            const int row = (r & 3) + 8 * (r >> 2) + 4 * h;
            gp[wv * 1024 + row * 32 + c] = gacc[r];
        }
    }
    __syncthreads();
    {
        float* gp = (float*)sFb;
        const int e = t * 4;
        float s[4] = {0.f, 0.f, 0.f, 0.f};
#pragma unroll
        for (int w = 0; w < 4; ++w) {
            float v[4];
            *(float4*)v = *(const float4*)&gp[w * 1024 + e];
#pragma unroll
            for (int j = 0; j < 4; ++j) s[j] += v[j];
        }
        *(float4*)&partial[(size_t)blockIdx.x * 1024 + e] = *(float4*)s;
    }
}

// ---------------------------------------------------------------------------
// Kernel 2: final gram reduce — nblk partials -> G[1024] in one pass.
// 4 blocks x 256; 4-way independent accumulators for load ILP; coalesced.
// ---------------------------------------------------------------------------
__global__ __launch_bounds__(256) void k_gfinal(
    const float* __restrict__ partial, float* __restrict__ Gf, int nblk)
{
    const int e = blockIdx.x * 256 + threadIdx.x;   // 0..1023
    float s0 = 0.f, s1 = 0.f, s2 = 0.f, s3 = 0.f;
    int b = 0;
    for (; b + 4 <= nblk; b += 4) {
        s0 += partial[(size_t)(b + 0) * 1024 + e];
        s1 += partial[(size_t)(b + 1) * 1024 + e];
        s2 += partial[(size_t)(b + 2) * 1024 + e];
        s3 += partial[(size_t)(b + 3) * 1024 + e];
    }
    for (; b < nblk; ++b) s0 += partial[(size_t)b * 1024 + e];
    Gf[e] = (s0 + s1) + (s2 + s3);
}

// ---------------------------------------------------------------------------
// Kernel 3: tail — conv2+BN+ReLU + conv3+BN+ReLU + mean.
// Branch-free convs via zero-padded LDS (G_pad 36x36, y1p 16x21x21);
// conv3 ic-loop fully unrolled with 4 independent accumulators.
// ---------------------------------------------------------------------------
__global__ __launch_bounds__(1024) void k_tail(
    const float* __restrict__ Gf,
    const float* __restrict__ w2, const float* __restrict__ b2,
    const float* __restrict__ g2, const float* __restrict__ bt2,
    const float* __restrict__ w3, const float* __restrict__ b3,
    const float* __restrict__ g3, const float* __restrict__ bt3,
    float* __restrict__ out)
{
    __shared__ float G_pad[36 * 36];     // 5.2 KB, zero halo 2
    __shared__ float y1[16 * 289];       // conv2 raw out (for BN stats)
    __shared__ float y1p[16 * 21 * 21];  // 28.2 KB, BN1+ReLU, zero halo 2
    __shared__ float y2[32 * 100];
    __shared__ float m1[16], r1[16];
    __shared__ float sw2[144], sp2[48];
    __shared__ float sw3[4608], sp3[96];

    const int t = threadIdx.x;

    // ---- phase 0: zero pads + stage weights (no deps) ----
    for (int i = t; i < 1296; i += 1024) G_pad[i] = 0.f;
    for (int i = t; i < 7056; i += 1024) y1p[i] = 0.f;
    for (int i = t; i < 144; i += 1024) sw2[i] = w2[i];
    for (int i = t; i < 4608; i += 1024) sw3[i] = w3[i];
    if (t < 16)              sp2[t]      = b2[t];
    else if (t < 32)         sp2[t]      = g2[t - 16];
    else if (t < 48)         sp2[t]      = bt2[t - 32];
    if (t >= 64 && t < 96)   sp3[t - 64] = b3[t - 64];
    else if (t >= 96 && t < 128)  sp3[t - 64] = g3[t - 96];
    else if (t >= 128 && t < 160) sp3[t - 64] = bt3[t - 128];
    const float g = Gf[t];               // one global load per thread
    __syncthreads();

    // ---- G into padded LDS ----
    G_pad[((t >> 5) + 2) * 36 + (t & 31) + 2] = g;
    __syncthreads();

    // ---- conv2 (branch-free): 16x17x17 ----
    for (int idx = t; idx < 16 * 289; idx += 1024) {
        const int oc = idx / 289;
        const int r  = idx - oc * 289;
        const int oy = r / 17, ox = r - (r / 17) * 17;
        const float* gp = &G_pad[(2 * oy) * 36 + 2 * ox];
        const float* wr = &sw2[oc * 9];
        float s = sp2[oc];
#pragma unroll
        for (int ky = 0; ky < 3; ++ky)
#pragma unroll
            for (int kx = 0; kx < 3; ++kx)
                s = fmaf(gp[ky * 36 + kx], wr[ky * 3 + kx], s);
        y1[idx] = s;
    }
    __syncthreads();

    // ---- BN1 stats: one wave per channel ----
    {
        const int ch = t >> 6, j = t & 63;
        float s = 0.f, ss = 0.f;
        for (int i = j; i < 289; i += 64) {
            float v = y1[ch * 289 + i];
            s += v; ss += v * v;
        }
#pragma unroll
        for (int o = 32; o; o >>= 1) { s += __shfl_xor(s, o); ss += __shfl_xor(ss, o); }
        if (j == 0) {
            float m = s * (1.f / 289.f);
            float var = ss * (1.f / 289.f) - m * m;
            m1[ch] = m;
            r1[ch] = rsqrtf(var + 1e-5f);
        }
    }
    __syncthreads();

    // ---- BN1 + ReLU -> padded y1p ----
    for (int idx = t; idx < 16 * 289; idx += 1024) {
        const int oc = idx / 289;
        const int r  = idx - oc * 289;
        const int oy = r / 17, ox = r - (r / 17) * 17;
        float v = (y1[idx] - m1[oc]) * r1[oc] * sp2[16 + oc] + sp2[32 + oc];
        y1p[oc * 441 + (oy + 2) * 21 + ox + 2] = v > 0.f ? v : 0.f;
    }
    __syncthreads();

    // ---- conv3 (branch-free, ic unrolled, 4 accumulators): 32x10x10 ----
    for (int idx = t; idx < 3200; idx += 1024) {
        const int oc = idx / 100;
        const int r  = idx - oc * 100;
        const int oy = r / 10, ox = r - (r / 10) * 10;
        float a0 = sp3[oc], a1 = 0.f, a2 = 0.f, a3 = 0.f;
#pragma unroll
        for (int ic = 0; ic < 16; ++ic) {
            const float* yi = &y1p[ic * 441 + (2 * oy) * 21 + 2 * ox];
            const float* wr = &sw3[(oc * 16 + ic) * 9];
            float p0 = 0.f, p1 = 0.f, p2 = 0.f;
#pragma unroll
            for (int kx = 0; kx < 3; ++kx) {
                p0 = fmaf(yi[kx],      wr[kx],     p0);
                p1 = fmaf(yi[21 + kx], wr[3 + kx], p1);
                p2 = fmaf(yi[42 + kx], wr[6 + kx], p2);
            }
            if ((ic & 3) == 0) a0 += p0 + p1 + p2;
            else if ((ic & 3) == 1) a1 += p0 + p1 + p2;
            else if ((ic & 3) == 2) a2 += p0 + p1 + p2;
            else a3 += p0 + p1 + p2;
        }
        y2[idx] = (a0 + a1) + (a2 + a3);
    }
    __syncthreads();

    // ---- BN2 + ReLU + spatial mean: 32 lanes per channel ----
    {
        const int ch = t >> 5, j = t & 31;
        float s = 0.f, ss = 0.f;
        for (int i = j; i < 100; i += 32) {
            float v = y2[ch * 100 + i];
            s += v; ss += v * v;
        }
#pragma unroll
        for (int o = 16; o; o >>= 1) { s += __shfl_xor(s, o); ss += __shfl_xor(ss, o); }
        const float m  = s * 0.01f;
        const float var = ss * 0.01f - m * m;
        const float rs = rsqrtf(var + 1e-5f);
        float a = 0.f;
        for (int i = j; i < 100; i += 32) {
            float v = (y2[ch * 100 + i] - m) * rs * sp3[32 + ch] + sp3[64 + ch];
            a += v > 0.f ? v : 0.f;
        }
#pragma unroll
        for (int o = 16; o; o >>= 1) a += __shfl_xor(a, o);
        if (j == 0) out[ch] = a * 0.01f;
    }
}

// ---------------------------------------------------------------------------
extern "C" void kernel_launch(void* const* d_in, const int* in_sizes, int n_in,
                              void* d_out, int out_size, void* d_ws, size_t ws_size,
                              hipStream_t stream)
{
    const float* x   = (const float*)d_in[0];
    const float* w1  = (const float*)d_in[1];
    const float* b1  = (const float*)d_in[2];
    const float* w2  = (const float*)d_in[3];
    const float* b2  = (const float*)d_in[4];
    const float* g2  = (const float*)d_in[5];
    const float* bt2 = (const float*)d_in[6];
    const float* w3  = (const float*)d_in[7];
    const float* b3  = (const float*)d_in[8];
    const float* g3  = (const float*)d_in[9];
    const float* bt3 = (const float*)d_in[10];

    size_t cap = ws_size / 4096;
    int nblk = (cap > (size_t)(NTILES + 1)) ? NTILES : (int)cap - 1;
    if (nblk > NTILES) nblk = NTILES;
    if (nblk < 256) nblk = 256;

    float* P   = (float*)d_ws;                 // [nblk][1024]
    float* Gf  = P + (size_t)nblk * 1024;      // [1024]
    float* out = (float*)d_out;

    k_conv_gram<<<nblk, 256, 0, stream>>>(x, w1, b1, P, nblk);
    k_gfinal<<<4, 256, 0, stream>>>(P, Gf, nblk);
    k_tail<<<1, 1024, 0, stream>>>(Gf, w2, b2, g2, bt2, w3, b3, g3, bt3, out);
}

// Round 8
// 89.991 us; speedup vs baseline: 4.4537x; 4.4537x over previous
//
#include <hip/hip_runtime.h>

#define NTILES_X 65          // ceil(1026/16)
#define NTILES   (65*65)     // 4225
#define OHW      1026
#define NCHUNK   32

typedef unsigned int  uint;
typedef unsigned short ushort;
typedef float  floatx16 __attribute__((ext_vector_type(16)));
typedef __bf16 bf16x8   __attribute__((ext_vector_type(8)));

__device__ __forceinline__ uint pk2f(float a, float b) {
    ushort lo = __builtin_bit_cast(ushort, (__bf16)a);
    ushort hi = __builtin_bit_cast(ushort, (__bf16)b);
    return (uint)lo | ((uint)hi << 16);
}
__device__ __forceinline__ bf16x8 frag_of(uint a, uint b, uint c, uint d) {
    uint4 u = make_uint4(a, b, c, d);
    return __builtin_bit_cast(bf16x8, u);
}
// k -> element offset in sInB[3][18][18]  (k = ic*9 + ky*3 + kx)
__device__ __forceinline__ constexpr int koff_of(int k) {
    return (k / 9) * 324 + ((k % 9) / 3) * 18 + (k % 3);
}
// one B-frag u16: slot k = (h ? kb : ka); ka,kb compile-time (kb = ka+8).
// k==27 is the bias slot (B=1.0); k>27 -> 0.
__device__ __forceinline__ uint bslot(const ushort* sInB, int base, int h, int ka, int kb) {
    if (kb < 27) {
        int off = h ? koff_of(kb) : koff_of(ka);
        return (uint)sInB[base + off];
    } else if (ka < 27) {
        uint cst = (kb == 27) ? 0x3F80u : 0u;
        uint rd  = (uint)sInB[base + koff_of(ka)];
        return h ? cst : rd;
    } else {
        uint ca = (ka == 27) ? 0x3F80u : 0u;
        uint cb = (kb == 27) ? 0x3F80u : 0u;
        return h ? cb : ca;
    }
}

// ---------------------------------------------------------------------------
// Kernel 1: conv1 (3->32, k3, pad2) via implicit-GEMM MFMA + MFMA bf16 gram.
// (unchanged — proven ~45 us)
// ---------------------------------------------------------------------------
__global__ __launch_bounds__(256, 4) void k_conv_gram(
    const float* __restrict__ x,   // [3][1024][1024]
    const float* __restrict__ w1,  // [32][3][3][3]
    const float* __restrict__ b1,  // [32]
    float* __restrict__ partial,   // [nblk][1024]
    int nblk)
{
    __shared__ __align__(16) ushort sInB[3*18*18];   // 1.9 KB bf16 input tile
    __shared__ __align__(16) ushort sFb[256*32];     // 16 KB bf16 F; aliased for reduce

    const int t    = threadIdx.x;
    const int wv   = t >> 6;
    const int lane = t & 63;
    const int h    = lane >> 5;
    const int c    = lane & 31;
    const int c4   = c >> 2, c3 = c & 3;

    // ---- weight(+bias) fragments, built once ----
    const float b1c = b1[c];
    uint wu0[4], wu1[4];
#pragma unroll
    for (int q = 0; q < 4; ++q) {
        {
            int k0 = h * 8 + 2 * q;
            wu0[q] = pk2f(w1[c * 27 + k0], w1[c * 27 + k0 + 1]);
        }
        {
            int k0 = 16 + h * 8 + 2 * q, k1 = k0 + 1;
            float r0 = w1[c * 27 + (k0 < 27 ? k0 : 26)];
            float r1 = w1[c * 27 + (k1 < 27 ? k1 : 26)];
            float v0 = (k0 < 27) ? r0 : (k0 == 27 ? b1c : 0.f);
            float v1 = (k1 < 27) ? r1 : (k1 == 27 ? b1c : 0.f);
            wu1[q] = pk2f(v0, v1);
        }
    }

    floatx16 gacc;
#pragma unroll
    for (int i = 0; i < 16; ++i) gacc[i] = 0.f;

    for (int tile = blockIdx.x; tile < NTILES; tile += nblk) {
        const int ty = tile / NTILES_X;
        const int tx = tile - ty * NTILES_X;
        const int by = ty * 16, bx = tx * 16;
        const bool interior = (ty >= 1) & (ty <= 62) & (tx >= 1) & (tx <= 62);

        __syncthreads();
        if (interior) {
            for (int i = t; i < 972; i += 256) {
                int ic = i / 324, rem = i - ic * 324, r = rem / 18, cc = rem - r * 18;
                float v = x[ic * 1048576 + (by - 2 + r) * 1024 + (bx - 2 + cc)];
                sInB[i] = __builtin_bit_cast(ushort, (__bf16)v);
            }
        } else {
            for (int i = t; i < 972; i += 256) {
                int ic = i / 324, rem = i - ic * 324, r = rem / 18, cc = rem - r * 18;
                int iy = by - 2 + r, ix = bx - 2 + cc;
                float v = 0.f;
                if ((unsigned)iy < 1024u && (unsigned)ix < 1024u)
                    v = x[ic * 1048576 + iy * 1024 + ix];
                sInB[i] = __builtin_bit_cast(ushort, (__bf16)v);
            }
        }
        __syncthreads();

#pragma unroll
        for (int e = 0; e < 2; ++e) {
            const int cb   = 2 * wv + e;
            const int px   = cb * 32 + c;
            const int base = (cb * 2 + (c >> 4)) * 18 + (c & 15);

            floatx16 cacc;
#pragma unroll
            for (int i = 0; i < 16; ++i) cacc[i] = 0.f;

            uint bu[4];
#pragma unroll
            for (int q = 0; q < 4; ++q) {
                uint lo = bslot(sInB, base, h, 2*q,     2*q + 8);
                uint hi = bslot(sInB, base, h, 2*q + 1, 2*q + 9);
                bu[q] = lo | (hi << 16);
            }
            cacc = __builtin_amdgcn_mfma_f32_32x32x16_bf16(
                frag_of(wu0[0], wu0[1], wu0[2], wu0[3]),
                frag_of(bu[0], bu[1], bu[2], bu[3]), cacc, 0, 0, 0);
#pragma unroll
            for (int q = 0; q < 4; ++q) {
                uint lo = bslot(sInB, base, h, 16 + 2*q,     16 + 2*q + 8);
                uint hi = bslot(sInB, base, h, 16 + 2*q + 1, 16 + 2*q + 9);
                bu[q] = lo | (hi << 16);
            }
            cacc = __builtin_amdgcn_mfma_f32_32x32x16_bf16(
                frag_of(wu1[0], wu1[1], wu1[2], wu1[3]),
                frag_of(bu[0], bu[1], bu[2], bu[3]), cacc, 0, 0, 0);

            const int py = px >> 4, pxx = px & 15;
            const uint vmask = ((by + py) < OHW && (bx + pxx) < OHW) ? 0xFFFFFFFFu : 0u;
#pragma unroll
            for (int q = 0; q < 4; ++q) {
                uint u0 = pk2f(cacc[4*q + 0], cacc[4*q + 1]) & vmask;
                uint u1 = pk2f(cacc[4*q + 2], cacc[4*q + 3]) & vmask;
                *(uint2*)&sFb[px * 32 + (((2*q + h) ^ (px & 7)) << 2)] = make_uint2(u0, u1);
            }
        }

#pragma unroll
        for (int s4 = 0; s4 < 4; ++s4) {
            const int pxg = wv * 64 + 16 * s4 + 8 * h;
            uint gu[4];
#pragma unroll
            for (int q = 0; q < 4; ++q) {
                const int j0 = 2 * q, j1 = 2 * q + 1;
                uint lo = sFb[(pxg + j0) * 32 + ((c4 ^ j0) << 2) + c3];
                uint hi = sFb[(pxg + j1) * 32 + ((c4 ^ j1) << 2) + c3];
                gu[q] = lo | (hi << 16);
            }
            bf16x8 gf = frag_of(gu[0], gu[1], gu[2], gu[3]);
            gacc = __builtin_amdgcn_mfma_f32_32x32x16_bf16(gf, gf, gacc, 0, 0, 0);
        }
    }

    __syncthreads();
    {
        float* gp = (float*)sFb;
#pragma unroll
        for (int r = 0; r < 16; ++r) {
            const int row = (r & 3) + 8 * (r >> 2) + 4 * h;
            gp[wv * 1024 + row * 32 + c] = gacc[r];
        }
    }
    __syncthreads();
    {
        float* gp = (float*)sFb;
        const int e = t * 4;
        float s[4] = {0.f, 0.f, 0.f, 0.f};
#pragma unroll
        for (int w = 0; w < 4; ++w) {
            float v[4];
            *(float4*)v = *(const float4*)&gp[w * 1024 + e];
#pragma unroll
            for (int j = 0; j < 4; ++j) s[j] += v[j];
        }
        *(float4*)&partial[(size_t)blockIdx.x * 1024 + e] = *(float4*)s;
    }
}

// ---------------------------------------------------------------------------
// Kernel 2a: reduce nblk partials -> NCHUNK partials. 32768 threads,
// coalesced (R6-proven; R7's 1024-thread version was a 350us latency chain).
// ---------------------------------------------------------------------------
__global__ __launch_bounds__(256) void k_reduce(
    const float* __restrict__ partial, float* __restrict__ partial2, int nblk)
{
    const int gt    = blockIdx.x * 256 + threadIdx.x;  // 0..32767
    const int e     = gt & 1023;
    const int chunk = gt >> 10;                        // 0..31
    float s = 0.f;
    for (int b = chunk; b < nblk; b += NCHUNK) s += partial[(size_t)b * 1024 + e];
    partial2[chunk * 1024 + e] = s;
}

// ---------------------------------------------------------------------------
// Kernel 2b: fold NCHUNK partials -> Gf[1024]. 1024 threads x 32 loads.
// ---------------------------------------------------------------------------
__global__ __launch_bounds__(256) void k_gfinal(
    const float* __restrict__ partial2, float* __restrict__ Gf)
{
    const int e = blockIdx.x * 256 + threadIdx.x;   // 0..1023
    float s0 = 0.f, s1 = 0.f, s2 = 0.f, s3 = 0.f;
#pragma unroll
    for (int k = 0; k < NCHUNK; k += 4) {
        s0 += partial2[(k + 0) * 1024 + e];
        s1 += partial2[(k + 1) * 1024 + e];
        s2 += partial2[(k + 2) * 1024 + e];
        s3 += partial2[(k + 3) * 1024 + e];
    }
    Gf[e] = (s0 + s1) + (s2 + s3);
}

// ---------------------------------------------------------------------------
// Kernel 3: tail — conv2+BN+ReLU + conv3+BN+ReLU + mean (R7 branch-free).
// ---------------------------------------------------------------------------
__global__ __launch_bounds__(1024) void k_tail(
    const float* __restrict__ Gf,
    const float* __restrict__ w2, const float* __restrict__ b2,
    const float* __restrict__ g2, const float* __restrict__ bt2,
    const float* __restrict__ w3, const float* __restrict__ b3,
    const float* __restrict__ g3, const float* __restrict__ bt3,
    float* __restrict__ out)
{
    __shared__ float G_pad[36 * 36];     // zero halo 2
    __shared__ float y1[16 * 289];       // conv2 raw out (for BN stats)
    __shared__ float y1p[16 * 21 * 21];  // BN1+ReLU, zero halo 2
    __shared__ float y2[32 * 100];
    __shared__ float m1[16], r1[16];
    __shared__ float sw2[144], sp2[48];
    __shared__ float sw3[4608], sp3[96];

    const int t = threadIdx.x;

    for (int i = t; i < 1296; i += 1024) G_pad[i] = 0.f;
    for (int i = t; i < 7056; i += 1024) y1p[i] = 0.f;
    for (int i = t; i < 144; i += 1024) sw2[i] = w2[i];
    for (int i = t; i < 4608; i += 1024) sw3[i] = w3[i];
    if (t < 16)              sp2[t]      = b2[t];
    else if (t < 32)         sp2[t]      = g2[t - 16];
    else if (t < 48)         sp2[t]      = bt2[t - 32];
    if (t >= 64 && t < 96)   sp3[t - 64] = b3[t - 64];
    else if (t >= 96 && t < 128)  sp3[t - 64] = g3[t - 96];
    else if (t >= 128 && t < 160) sp3[t - 64] = bt3[t - 128];
    const float g = Gf[t];               // one global load per thread
    __syncthreads();

    G_pad[((t >> 5) + 2) * 36 + (t & 31) + 2] = g;
    __syncthreads();

    // ---- conv2 (branch-free): 16x17x17 ----
    for (int idx = t; idx < 16 * 289; idx += 1024) {
        const int oc = idx / 289;
        const int r  = idx - oc * 289;
        const int oy = r / 17, ox = r - (r / 17) * 17;
        const float* gp = &G_pad[(2 * oy) * 36 + 2 * ox];
        const float* wr = &sw2[oc * 9];
        float s = sp2[oc];
#pragma unroll
        for (int ky = 0; ky < 3; ++ky)
#pragma unroll
            for (int kx = 0; kx < 3; ++kx)
                s = fmaf(gp[ky * 36 + kx], wr[ky * 3 + kx], s);
        y1[idx] = s;
    }
    __syncthreads();

    // ---- BN1 stats: one wave per channel ----
    {
        const int ch = t >> 6, j = t & 63;
        float s = 0.f, ss = 0.f;
        for (int i = j; i < 289; i += 64) {
            float v = y1[ch * 289 + i];
            s += v; ss += v * v;
        }
#pragma unroll
        for (int o = 32; o; o >>= 1) { s += __shfl_xor(s, o); ss += __shfl_xor(ss, o); }
        if (j == 0) {
            float m = s * (1.f / 289.f);
            float var = ss * (1.f / 289.f) - m * m;
            m1[ch] = m;
            r1[ch] = rsqrtf(var + 1e-5f);
        }
    }
    __syncthreads();

    // ---- BN1 + ReLU -> padded y1p ----
    for (int idx = t; idx < 16 * 289; idx += 1024) {
        const int oc = idx / 289;
        const int r  = idx - oc * 289;
        const int oy = r / 17, ox = r - (r / 17) * 17;
        float v = (y1[idx] - m1[oc]) * r1[oc] * sp2[16 + oc] + sp2[32 + oc];
        y1p[oc * 441 + (oy + 2) * 21 + ox + 2] = v > 0.f ? v : 0.f;
    }
    __syncthreads();

    // ---- conv3 (branch-free, ic unrolled, 4 accumulators): 32x10x10 ----
    for (int idx = t; idx < 3200; idx += 1024) {
        const int oc = idx / 100;
        const int r  = idx - oc * 100;
        const int oy = r / 10, ox = r - (r / 10) * 10;
        float a0 = sp3[oc], a1 = 0.f, a2 = 0.f, a3 = 0.f;
#pragma unroll
        for (int ic = 0; ic < 16; ++ic) {
            const float* yi = &y1p[ic * 441 + (2 * oy) * 21 + 2 * ox];
            const float* wr = &sw3[(oc * 16 + ic) * 9];
            float p0 = 0.f, p1 = 0.f, p2 = 0.f;
#pragma unroll
            for (int kx = 0; kx < 3; ++kx) {
                p0 = fmaf(yi[kx],      wr[kx],     p0);
                p1 = fmaf(yi[21 + kx], wr[3 + kx], p1);
                p2 = fmaf(yi[42 + kx], wr[6 + kx], p2);
            }
            if ((ic & 3) == 0) a0 += p0 + p1 + p2;
            else if ((ic & 3) == 1) a1 += p0 + p1 + p2;
            else if ((ic & 3) == 2) a2 += p0 + p1 + p2;
            else a3 += p0 + p1 + p2;
        }
        y2[idx] = (a0 + a1) + (a2 + a3);
    }
    __syncthreads();

    // ---- BN2 + ReLU + spatial mean: 32 lanes per channel ----
    {
        const int ch = t >> 5, j = t & 31;
        float s = 0.f, ss = 0.f;
        for (int i = j; i < 100; i += 32) {
            float v = y2[ch * 100 + i];
            s += v; ss += v * v;
        }
#pragma unroll
        for (int o = 16; o; o >>= 1) { s += __shfl_xor(s, o); ss += __shfl_xor(ss, o); }
        const float m  = s * 0.01f;
        const float var = ss * 0.01f - m * m;
        const float rs = rsqrtf(var + 1e-5f);
        float a = 0.f;
        for (int i = j; i < 100; i += 32) {
            float v = (y2[ch * 100 + i] - m) * rs * sp3[32 + ch] + sp3[64 + ch];
            a += v > 0.f ? v : 0.f;
        }
#pragma unroll
        for (int o = 16; o; o >>= 1) a += __shfl_xor(a, o);
        if (j == 0) out[ch] = a * 0.01f;
    }
}

// ---------------------------------------------------------------------------
extern "C" void kernel_launch(void* const* d_in, const int* in_sizes, int n_in,
                              void* d_out, int out_size, void* d_ws, size_t ws_size,
                              hipStream_t stream)
{
    const float* x   = (const float*)d_in[0];
    const float* w1  = (const float*)d_in[1];
    const float* b1  = (const float*)d_in[2];
    const float* w2  = (const float*)d_in[3];
    const float* b2  = (const float*)d_in[4];
    const float* g2  = (const float*)d_in[5];
    const float* bt2 = (const float*)d_in[6];
    const float* w3  = (const float*)d_in[7];
    const float* b3  = (const float*)d_in[8];
    const float* g3  = (const float*)d_in[9];
    const float* bt3 = (const float*)d_in[10];

    size_t cap = ws_size / 4096;
    int nblk = (cap > (size_t)(NTILES + NCHUNK + 1)) ? NTILES : (int)cap - NCHUNK - 1;
    if (nblk > NTILES) nblk = NTILES;
    if (nblk < 256) nblk = 256;

    float* P   = (float*)d_ws;                  // [nblk][1024]
    float* P2  = P + (size_t)nblk * 1024;       // [NCHUNK][1024]
    float* Gf  = P2 + (size_t)NCHUNK * 1024;    // [1024]
    float* out = (float*)d_out;

    k_conv_gram<<<nblk, 256, 0, stream>>>(x, w1, b1, P, nblk);
    k_reduce<<<128, 256, 0, stream>>>(P, P2, nblk);
    k_gfinal<<<4, 256, 0, stream>>>(P2, Gf);
    k_tail<<<1, 1024, 0, stream>>>(Gf, w2, b2, g2, bt2, w3, b3, g3, bt3, out);
}

// Round 9
// 88.500 us; speedup vs baseline: 4.5287x; 1.0168x over previous
//
#include <hip/hip_runtime.h>

#define NTILES_X 65          // ceil(1026/16)
#define NTILES   (65*65)     // 4225
#define OHW      1026
#define NCHUNK   32
#define NBLK_MAX 2048        // 8 blocks/CU x 256 CUs co-resident

typedef unsigned int  uint;
typedef unsigned short ushort;
typedef float  floatx16 __attribute__((ext_vector_type(16)));
typedef __bf16 bf16x8   __attribute__((ext_vector_type(8)));

__device__ __forceinline__ uint pk2f(float a, float b) {
    ushort lo = __builtin_bit_cast(ushort, (__bf16)a);
    ushort hi = __builtin_bit_cast(ushort, (__bf16)b);
    return (uint)lo | ((uint)hi << 16);
}
__device__ __forceinline__ bf16x8 frag_of(uint a, uint b, uint c, uint d) {
    uint4 u = make_uint4(a, b, c, d);
    return __builtin_bit_cast(bf16x8, u);
}
// k -> element offset in sInB[3][18][18]  (k = ic*9 + ky*3 + kx)
__device__ __forceinline__ constexpr int koff_of(int k) {
    return (k / 9) * 324 + ((k % 9) / 3) * 18 + (k % 3);
}
// one B-frag u16: slot k = (h ? kb : ka); ka,kb compile-time (kb = ka+8).
// k==27 is the bias slot (B=1.0); k>27 -> 0.
__device__ __forceinline__ uint bslot(const ushort* sInB, int base, int h, int ka, int kb) {
    if (kb < 27) {
        int off = h ? koff_of(kb) : koff_of(ka);
        return (uint)sInB[base + off];
    } else if (ka < 27) {
        uint cst = (kb == 27) ? 0x3F80u : 0u;
        uint rd  = (uint)sInB[base + koff_of(ka)];
        return h ? cst : rd;
    } else {
        uint ca = (ka == 27) ? 0x3F80u : 0u;
        uint cb = (kb == 27) ? 0x3F80u : 0u;
        return h ? cb : ca;
    }
}

// ---------------------------------------------------------------------------
// Kernel 1: conv1 (3->32, k3, pad2) via implicit-GEMM MFMA + MFMA bf16 gram.
// R8 compiled to exactly 64 VGPR / 20480 B LDS == the 8-blocks/CU breakpoint;
// (256,8) claims it. (R4 lesson: only force a cap the allocator already meets.)
// ---------------------------------------------------------------------------
__global__ __launch_bounds__(256, 8) void k_conv_gram(
    const float* __restrict__ x,   // [3][1024][1024]
    const float* __restrict__ w1,  // [32][3][3][3]
    const float* __restrict__ b1,  // [32]
    float* __restrict__ partial,   // [nblk][1024]
    int nblk)
{
    __shared__ __align__(16) ushort sInB[3*18*18];   // 1.9 KB bf16 input tile
    __shared__ __align__(16) ushort sFb[256*32];     // 16 KB bf16 F; aliased for reduce

    const int t    = threadIdx.x;
    const int wv   = t >> 6;
    const int lane = t & 63;
    const int h    = lane >> 5;
    const int c    = lane & 31;
    const int c4   = c >> 2, c3 = c & 3;

    // ---- weight(+bias) fragments, built once ----
    const float b1c = b1[c];
    uint wu0[4], wu1[4];
#pragma unroll
    for (int q = 0; q < 4; ++q) {
        {
            int k0 = h * 8 + 2 * q;
            wu0[q] = pk2f(w1[c * 27 + k0], w1[c * 27 + k0 + 1]);
        }
        {
            int k0 = 16 + h * 8 + 2 * q, k1 = k0 + 1;
            float r0 = w1[c * 27 + (k0 < 27 ? k0 : 26)];
            float r1 = w1[c * 27 + (k1 < 27 ? k1 : 26)];
            float v0 = (k0 < 27) ? r0 : (k0 == 27 ? b1c : 0.f);
            float v1 = (k1 < 27) ? r1 : (k1 == 27 ? b1c : 0.f);
            wu1[q] = pk2f(v0, v1);
        }
    }

    floatx16 gacc;
#pragma unroll
    for (int i = 0; i < 16; ++i) gacc[i] = 0.f;

    for (int tile = blockIdx.x; tile < NTILES; tile += nblk) {
        const int ty = tile / NTILES_X;
        const int tx = tile - ty * NTILES_X;
        const int by = ty * 16, bx = tx * 16;
        const bool interior = (ty >= 1) & (ty <= 62) & (tx >= 1) & (tx <= 62);

        __syncthreads();
        if (interior) {
            for (int i = t; i < 972; i += 256) {
                int ic = i / 324, rem = i - ic * 324, r = rem / 18, cc = rem - r * 18;
                float v = x[ic * 1048576 + (by - 2 + r) * 1024 + (bx - 2 + cc)];
                sInB[i] = __builtin_bit_cast(ushort, (__bf16)v);
            }
        } else {
            for (int i = t; i < 972; i += 256) {
                int ic = i / 324, rem = i - ic * 324, r = rem / 18, cc = rem - r * 18;
                int iy = by - 2 + r, ix = bx - 2 + cc;
                float v = 0.f;
                if ((unsigned)iy < 1024u && (unsigned)ix < 1024u)
                    v = x[ic * 1048576 + iy * 1024 + ix];
                sInB[i] = __builtin_bit_cast(ushort, (__bf16)v);
            }
        }
        __syncthreads();

#pragma unroll
        for (int e = 0; e < 2; ++e) {
            const int cb   = 2 * wv + e;
            const int px   = cb * 32 + c;
            const int base = (cb * 2 + (c >> 4)) * 18 + (c & 15);

            floatx16 cacc;
#pragma unroll
            for (int i = 0; i < 16; ++i) cacc[i] = 0.f;

            uint bu[4];
#pragma unroll
            for (int q = 0; q < 4; ++q) {
                uint lo = bslot(sInB, base, h, 2*q,     2*q + 8);
                uint hi = bslot(sInB, base, h, 2*q + 1, 2*q + 9);
                bu[q] = lo | (hi << 16);
            }
            cacc = __builtin_amdgcn_mfma_f32_32x32x16_bf16(
                frag_of(wu0[0], wu0[1], wu0[2], wu0[3]),
                frag_of(bu[0], bu[1], bu[2], bu[3]), cacc, 0, 0, 0);
#pragma unroll
            for (int q = 0; q < 4; ++q) {
                uint lo = bslot(sInB, base, h, 16 + 2*q,     16 + 2*q + 8);
                uint hi = bslot(sInB, base, h, 16 + 2*q + 1, 16 + 2*q + 9);
                bu[q] = lo | (hi << 16);
            }
            cacc = __builtin_amdgcn_mfma_f32_32x32x16_bf16(
                frag_of(wu1[0], wu1[1], wu1[2], wu1[3]),
                frag_of(bu[0], bu[1], bu[2], bu[3]), cacc, 0, 0, 0);

            const int py = px >> 4, pxx = px & 15;
            const uint vmask = ((by + py) < OHW && (bx + pxx) < OHW) ? 0xFFFFFFFFu : 0u;
#pragma unroll
            for (int q = 0; q < 4; ++q) {
                uint u0 = pk2f(cacc[4*q + 0], cacc[4*q + 1]) & vmask;
                uint u1 = pk2f(cacc[4*q + 2], cacc[4*q + 3]) & vmask;
                *(uint2*)&sFb[px * 32 + (((2*q + h) ^ (px & 7)) << 2)] = make_uint2(u0, u1);
            }
        }

#pragma unroll
        for (int s4 = 0; s4 < 4; ++s4) {
            const int pxg = wv * 64 + 16 * s4 + 8 * h;
            uint gu[4];
#pragma unroll
            for (int q = 0; q < 4; ++q) {
                const int j0 = 2 * q, j1 = 2 * q + 1;
                uint lo = sFb[(pxg + j0) * 32 + ((c4 ^ j0) << 2) + c3];
                uint hi = sFb[(pxg + j1) * 32 + ((c4 ^ j1) << 2) + c3];
                gu[q] = lo | (hi << 16);
            }
            bf16x8 gf = frag_of(gu[0], gu[1], gu[2], gu[3]);
            gacc = __builtin_amdgcn_mfma_f32_32x32x16_bf16(gf, gf, gacc, 0, 0, 0);
        }
    }

    __syncthreads();
    {
        float* gp = (float*)sFb;
#pragma unroll
        for (int r = 0; r < 16; ++r) {
            const int row = (r & 3) + 8 * (r >> 2) + 4 * h;
            gp[wv * 1024 + row * 32 + c] = gacc[r];
        }
    }
    __syncthreads();
    {
        float* gp = (float*)sFb;
        const int e = t * 4;
        float s[4] = {0.f, 0.f, 0.f, 0.f};
#pragma unroll
        for (int w = 0; w < 4; ++w) {
            float v[4];
            *(float4*)v = *(const float4*)&gp[w * 1024 + e];
#pragma unroll
            for (int j = 0; j < 4; ++j) s[j] += v[j];
        }
        *(float4*)&partial[(size_t)blockIdx.x * 1024 + e] = *(float4*)s;
    }
}

// ---------------------------------------------------------------------------
// Kernel 2: reduce nblk partials -> NCHUNK partials. 32768 threads, coalesced.
// ---------------------------------------------------------------------------
__global__ __launch_bounds__(256) void k_reduce(
    const float* __restrict__ partial, float* __restrict__ partial2, int nblk)
{
    const int gt    = blockIdx.x * 256 + threadIdx.x;  // 0..32767
    const int e     = gt & 1023;
    const int chunk = gt >> 10;                        // 0..31
    float s = 0.f;
    for (int b = chunk; b < nblk; b += NCHUNK) s += partial[(size_t)b * 1024 + e];
    partial2[chunk * 1024 + e] = s;
}

// ---------------------------------------------------------------------------
// Kernel 3: tail — gram fold (32 ILP loads) + conv2+BN+ReLU + conv3+BN+ReLU
// + mean. Branch-free convs via zero-padded LDS.
// ---------------------------------------------------------------------------
__global__ __launch_bounds__(1024) void k_tail(
    const float* __restrict__ partial2,   // [NCHUNK][1024]
    const float* __restrict__ w2, const float* __restrict__ b2,
    const float* __restrict__ g2, const float* __restrict__ bt2,
    const float* __restrict__ w3, const float* __restrict__ b3,
    const float* __restrict__ g3, const float* __restrict__ bt3,
    float* __restrict__ out)
{
    __shared__ float G_pad[36 * 36];     // zero halo 2
    __shared__ float y1[16 * 289];       // conv2 raw out (for BN stats)
    __shared__ float y1p[16 * 21 * 21];  // BN1+ReLU, zero halo 2
    __shared__ float y2[32 * 100];
    __shared__ float m1[16], r1[16];
    __shared__ float sw2[144], sp2[48];
    __shared__ float sw3[4608], sp3[96];

    const int t = threadIdx.x;

    // ---- phase 0: gram fold + zero pads + stage weights (independent) ----
    float s0 = 0.f, s1 = 0.f, s2 = 0.f, s3 = 0.f;
#pragma unroll
    for (int k = 0; k < NCHUNK; k += 4) {
        s0 += partial2[(k + 0) * 1024 + t];
        s1 += partial2[(k + 1) * 1024 + t];
        s2 += partial2[(k + 2) * 1024 + t];
        s3 += partial2[(k + 3) * 1024 + t];
    }
    const float g = (s0 + s1) + (s2 + s3);

    for (int i = t; i < 1296; i += 1024) G_pad[i] = 0.f;
    for (int i = t; i < 7056; i += 1024) y1p[i] = 0.f;
    for (int i = t; i < 144; i += 1024) sw2[i] = w2[i];
    for (int i = t; i < 4608; i += 1024) sw3[i] = w3[i];
    if (t < 16)              sp2[t]      = b2[t];
    else if (t < 32)         sp2[t]      = g2[t - 16];
    else if (t < 48)         sp2[t]      = bt2[t - 32];
    if (t >= 64 && t < 96)   sp3[t - 64] = b3[t - 64];
    else if (t >= 96 && t < 128)  sp3[t - 64] = g3[t - 96];
    else if (t >= 128 && t < 160) sp3[t - 64] = bt3[t - 128];
    __syncthreads();

    G_pad[((t >> 5) + 2) * 36 + (t & 31) + 2] = g;
    __syncthreads();

    // ---- conv2 (branch-free): 16x17x17 ----
    for (int idx = t; idx < 16 * 289; idx += 1024) {
        const int oc = idx / 289;
        const int r  = idx - oc * 289;
        const int oy = r / 17, ox = r - (r / 17) * 17;
        const float* gp = &G_pad[(2 * oy) * 36 + 2 * ox];
        const float* wr = &sw2[oc * 9];
        float s = sp2[oc];
#pragma unroll
        for (int ky = 0; ky < 3; ++ky)
#pragma unroll
            for (int kx = 0; kx < 3; ++kx)
                s = fmaf(gp[ky * 36 + kx], wr[ky * 3 + kx], s);
        y1[idx] = s;
    }
    __syncthreads();

    // ---- BN1 stats: one wave per channel ----
    {
        const int ch = t >> 6, j = t & 63;
        float s = 0.f, ss = 0.f;
        for (int i = j; i < 289; i += 64) {
            float v = y1[ch * 289 + i];
            s += v; ss += v * v;
        }
#pragma unroll
        for (int o = 32; o; o >>= 1) { s += __shfl_xor(s, o); ss += __shfl_xor(ss, o); }
        if (j == 0) {
            float m = s * (1.f / 289.f);
            float var = ss * (1.f / 289.f) - m * m;
            m1[ch] = m;
            r1[ch] = rsqrtf(var + 1e-5f);
        }
    }
    __syncthreads();

    // ---- BN1 + ReLU -> padded y1p ----
    for (int idx = t; idx < 16 * 289; idx += 1024) {
        const int oc = idx / 289;
        const int r  = idx - oc * 289;
        const int oy = r / 17, ox = r - (r / 17) * 17;
        float v = (y1[idx] - m1[oc]) * r1[oc] * sp2[16 + oc] + sp2[32 + oc];
        y1p[oc * 441 + (oy + 2) * 21 + ox + 2] = v > 0.f ? v : 0.f;
    }
    __syncthreads();

    // ---- conv3 (branch-free, ic unrolled, 4 accumulators): 32x10x10 ----
    for (int idx = t; idx < 3200; idx += 1024) {
        const int oc = idx / 100;
        const int r  = idx - oc * 100;
        const int oy = r / 10, ox = r - (r / 10) * 10;
        float a0 = sp3[oc], a1 = 0.f, a2 = 0.f, a3 = 0.f;
#pragma unroll
        for (int ic = 0; ic < 16; ++ic) {
            const float* yi = &y1p[ic * 441 + (2 * oy) * 21 + 2 * ox];
            const float* wr = &sw3[(oc * 16 + ic) * 9];
            float p0 = 0.f, p1 = 0.f, p2 = 0.f;
#pragma unroll
            for (int kx = 0; kx < 3; ++kx) {
                p0 = fmaf(yi[kx],      wr[kx],     p0);
                p1 = fmaf(yi[21 + kx], wr[3 + kx], p1);
                p2 = fmaf(yi[42 + kx], wr[6 + kx], p2);
            }
            if ((ic & 3) == 0) a0 += p0 + p1 + p2;
            else if ((ic & 3) == 1) a1 += p0 + p1 + p2;
            else if ((ic & 3) == 2) a2 += p0 + p1 + p2;
            else a3 += p0 + p1 + p2;
        }
        y2[idx] = (a0 + a1) + (a2 + a3);
    }
    __syncthreads();

    // ---- BN2 + ReLU + spatial mean: 32 lanes per channel ----
    {
        const int ch = t >> 5, j = t & 31;
        float s = 0.f, ss = 0.f;
        for (int i = j; i < 100; i += 32) {
            float v = y2[ch * 100 + i];
            s += v; ss += v * v;
        }
#pragma unroll
        for (int o = 16; o; o >>= 1) { s += __shfl_xor(s, o); ss += __shfl_xor(ss, o); }
        const float m  = s * 0.01f;
        const float var = ss * 0.01f - m * m;
        const float rs = rsqrtf(var + 1e-5f);
        float a = 0.f;
        for (int i = j; i < 100; i += 32) {
            float v = (y2[ch * 100 + i] - m) * rs * sp3[32 + ch] + sp3[64 + ch];
            a += v > 0.f ? v : 0.f;
        }
#pragma unroll
        for (int o = 16; o; o >>= 1) a += __shfl_xor(a, o);
        if (j == 0) out[ch] = a * 0.01f;
    }
}

// ---------------------------------------------------------------------------
extern "C" void kernel_launch(void* const* d_in, const int* in_sizes, int n_in,
                              void* d_out, int out_size, void* d_ws, size_t ws_size,
                              hipStream_t stream)
{
    const float* x   = (const float*)d_in[0];
    const float* w1  = (const float*)d_in[1];
    const float* b1  = (const float*)d_in[2];
    const float* w2  = (const float*)d_in[3];
    const float* b2  = (const float*)d_in[4];
    const float* g2  = (const float*)d_in[5];
    const float* bt2 = (const float*)d_in[6];
    const float* w3  = (const float*)d_in[7];
    const float* b3  = (const float*)d_in[8];
    const float* g3  = (const float*)d_in[9];
    const float* bt3 = (const float*)d_in[10];

    size_t cap = ws_size / 4096;               // 1024-float slots available
    int nblk = NBLK_MAX;
    if ((size_t)(nblk + NCHUNK) > cap) nblk = (int)cap - NCHUNK;
    if (nblk > NBLK_MAX) nblk = NBLK_MAX;
    if (nblk < 256) nblk = 256;

    float* P   = (float*)d_ws;                  // [nblk][1024]
    float* P2  = P + (size_t)nblk * 1024;       // [NCHUNK][1024]
    float* out = (float*)d_out;

    k_conv_gram<<<nblk, 256, 0, stream>>>(x, w1, b1, P, nblk);
    k_reduce<<<128, 256, 0, stream>>>(P, P2, nblk);
    k_tail<<<1, 1024, 0, stream>>>(P2, w2, b2, g2, bt2, w3, b3, g3, bt3, out);
}

// Round 10
// 66.212 us; speedup vs baseline: 6.0532x; 1.3366x over previous
//
#include <hip/hip_runtime.h>

#define NTILES_X 65          // ceil(1026/16)
#define NTILES   (65*65)     // 4225
#define OHW      1026
#define NCHUNK   32
#define NBLK_MAX 2048
#define NXCD     8
#define BAND     529         // ceil(NTILES/NXCD)

typedef unsigned int  uint;
typedef unsigned short ushort;
typedef float  floatx16 __attribute__((ext_vector_type(16)));
typedef __bf16 bf16x8   __attribute__((ext_vector_type(8)));

__device__ __forceinline__ uint pk2f(float a, float b) {
    ushort lo = __builtin_bit_cast(ushort, (__bf16)a);
    ushort hi = __builtin_bit_cast(ushort, (__bf16)b);
    return (uint)lo | ((uint)hi << 16);
}
__device__ __forceinline__ bf16x8 frag_of(uint a, uint b, uint c, uint d) {
    uint4 u = make_uint4(a, b, c, d);
    return __builtin_bit_cast(bf16x8, u);
}
// k -> element offset in sInB[3][18][18]  (k = ic*9 + ky*3 + kx)
__device__ __forceinline__ constexpr int koff_of(int k) {
    return (k / 9) * 324 + ((k % 9) / 3) * 18 + (k % 3);
}
// one B-frag u16: slot k = (h ? kb : ka); ka,kb compile-time (kb = ka+8).
// k==27 is the bias slot (B=1.0); k>27 -> 0.
__device__ __forceinline__ uint bslot(const ushort* sInB, int base, int h, int ka, int kb) {
    if (kb < 27) {
        int off = h ? koff_of(kb) : koff_of(ka);
        return (uint)sInB[base + off];
    } else if (ka < 27) {
        uint cst = (kb == 27) ? 0x3F80u : 0u;
        uint rd  = (uint)sInB[base + koff_of(ka)];
        return h ? cst : rd;
    } else {
        uint ca = (ka == 27) ? 0x3F80u : 0u;
        uint cb = (kb == 27) ? 0x3F80u : 0u;
        return h ? cb : ca;
    }
}

// ---------------------------------------------------------------------------
// Kernel 1: conv1 (3->32, k3, pad2) via implicit-GEMM MFMA + MFMA bf16 gram.
// (256,4): 64 VGPR, no spills (R9's (256,8) -> 32 VGPR -> 59 MB scratch).
// XCD-banded tiles: blockIdx%8 -> contiguous tile band, so each XCD's L2
// sees ~1/8 of the image instead of all of it (R9 FETCH 78 MB vs 12.6 input).
// ---------------------------------------------------------------------------
__global__ __launch_bounds__(256, 4) void k_conv_gram(
    const float* __restrict__ x,   // [3][1024][1024]
    const float* __restrict__ w1,  // [32][3][3][3]
    const float* __restrict__ b1,  // [32]
    float* __restrict__ partial,   // [nblk][1024]
    int nblk)
{
    __shared__ __align__(16) ushort sInB[3*18*18];   // 1.9 KB bf16 input tile
    __shared__ __align__(16) ushort sFb[256*32];     // 16 KB bf16 F; aliased for reduce

    const int t    = threadIdx.x;
    const int wv   = t >> 6;
    const int lane = t & 63;
    const int h    = lane >> 5;
    const int c    = lane & 31;
    const int c4   = c >> 2, c3 = c & 3;

    // ---- weight(+bias) fragments, built once ----
    const float b1c = b1[c];
    uint wu0[4], wu1[4];
#pragma unroll
    for (int q = 0; q < 4; ++q) {
        {
            int k0 = h * 8 + 2 * q;
            wu0[q] = pk2f(w1[c * 27 + k0], w1[c * 27 + k0 + 1]);
        }
        {
            int k0 = 16 + h * 8 + 2 * q, k1 = k0 + 1;
            float r0 = w1[c * 27 + (k0 < 27 ? k0 : 26)];
            float r1 = w1[c * 27 + (k1 < 27 ? k1 : 26)];
            float v0 = (k0 < 27) ? r0 : (k0 == 27 ? b1c : 0.f);
            float v1 = (k1 < 27) ? r1 : (k1 == 27 ? b1c : 0.f);
            wu1[q] = pk2f(v0, v1);
        }
    }

    floatx16 gacc;
#pragma unroll
    for (int i = 0; i < 16; ++i) gacc[i] = 0.f;

    // XCD band: performance-only heuristic (correct for ANY dispatch order)
    const int xcd    = blockIdx.x & (NXCD - 1);
    const int lb     = blockIdx.x >> 3;          // 0..nblk/8-1
    const int nb_per = nblk >> 3;
    const int tstart = xcd * BAND;
    const int tend   = (tstart + BAND < NTILES) ? tstart + BAND : NTILES;

    for (int tile = tstart + lb; tile < tend; tile += nb_per) {
        const int ty = tile / NTILES_X;
        const int tx = tile - ty * NTILES_X;
        const int by = ty * 16, bx = tx * 16;
        const bool interior = (ty >= 1) & (ty <= 62) & (tx >= 1) & (tx <= 62);

        __syncthreads();
        if (interior) {
            for (int i = t; i < 972; i += 256) {
                int ic = i / 324, rem = i - ic * 324, r = rem / 18, cc = rem - r * 18;
                float v = x[ic * 1048576 + (by - 2 + r) * 1024 + (bx - 2 + cc)];
                sInB[i] = __builtin_bit_cast(ushort, (__bf16)v);
            }
        } else {
            for (int i = t; i < 972; i += 256) {
                int ic = i / 324, rem = i - ic * 324, r = rem / 18, cc = rem - r * 18;
                int iy = by - 2 + r, ix = bx - 2 + cc;
                float v = 0.f;
                if ((unsigned)iy < 1024u && (unsigned)ix < 1024u)
                    v = x[ic * 1048576 + iy * 1024 + ix];
                sInB[i] = __builtin_bit_cast(ushort, (__bf16)v);
            }
        }
        __syncthreads();

#pragma unroll
        for (int e = 0; e < 2; ++e) {
            const int cb   = 2 * wv + e;
            const int px   = cb * 32 + c;
            const int base = (cb * 2 + (c >> 4)) * 18 + (c & 15);

            floatx16 cacc;
#pragma unroll
            for (int i = 0; i < 16; ++i) cacc[i] = 0.f;

            uint bu[4];
#pragma unroll
            for (int q = 0; q < 4; ++q) {
                uint lo = bslot(sInB, base, h, 2*q,     2*q + 8);
                uint hi = bslot(sInB, base, h, 2*q + 1, 2*q + 9);
                bu[q] = lo | (hi << 16);
            }
            cacc = __builtin_amdgcn_mfma_f32_32x32x16_bf16(
                frag_of(wu0[0], wu0[1], wu0[2], wu0[3]),
                frag_of(bu[0], bu[1], bu[2], bu[3]), cacc, 0, 0, 0);
#pragma unroll
            for (int q = 0; q < 4; ++q) {
                uint lo = bslot(sInB, base, h, 16 + 2*q,     16 + 2*q + 8);
                uint hi = bslot(sInB, base, h, 16 + 2*q + 1, 16 + 2*q + 9);
                bu[q] = lo | (hi << 16);
            }
            cacc = __builtin_amdgcn_mfma_f32_32x32x16_bf16(
                frag_of(wu1[0], wu1[1], wu1[2], wu1[3]),
                frag_of(bu[0], bu[1], bu[2], bu[3]), cacc, 0, 0, 0);

            const int py = px >> 4, pxx = px & 15;
            const uint vmask = ((by + py) < OHW && (bx + pxx) < OHW) ? 0xFFFFFFFFu : 0u;
#pragma unroll
            for (int q = 0; q < 4; ++q) {
                uint u0 = pk2f(cacc[4*q + 0], cacc[4*q + 1]) & vmask;
                uint u1 = pk2f(cacc[4*q + 2], cacc[4*q + 3]) & vmask;
                *(uint2*)&sFb[px * 32 + (((2*q + h) ^ (px & 7)) << 2)] = make_uint2(u0, u1);
            }
        }

#pragma unroll
        for (int s4 = 0; s4 < 4; ++s4) {
            const int pxg = wv * 64 + 16 * s4 + 8 * h;
            uint gu[4];
#pragma unroll
            for (int q = 0; q < 4; ++q) {
                const int j0 = 2 * q, j1 = 2 * q + 1;
                uint lo = sFb[(pxg + j0) * 32 + ((c4 ^ j0) << 2) + c3];
                uint hi = sFb[(pxg + j1) * 32 + ((c4 ^ j1) << 2) + c3];
                gu[q] = lo | (hi << 16);
            }
            bf16x8 gf = frag_of(gu[0], gu[1], gu[2], gu[3]);
            gacc = __builtin_amdgcn_mfma_f32_32x32x16_bf16(gf, gf, gacc, 0, 0, 0);
        }
    }

    __syncthreads();
    {
        float* gp = (float*)sFb;
#pragma unroll
        for (int r = 0; r < 16; ++r) {
            const int row = (r & 3) + 8 * (r >> 2) + 4 * h;
            gp[wv * 1024 + row * 32 + c] = gacc[r];
        }
    }
    __syncthreads();
    {
        float* gp = (float*)sFb;
        const int e = t * 4;
        float s[4] = {0.f, 0.f, 0.f, 0.f};
#pragma unroll
        for (int w = 0; w < 4; ++w) {
            float v[4];
            *(float4*)v = *(const float4*)&gp[w * 1024 + e];
#pragma unroll
            for (int j = 0; j < 4; ++j) s[j] += v[j];
        }
        *(float4*)&partial[(size_t)blockIdx.x * 1024 + e] = *(float4*)s;
    }
}

// ---------------------------------------------------------------------------
// Kernel 2: reduce nblk partials -> NCHUNK partials. 32768 threads, coalesced.
// ---------------------------------------------------------------------------
__global__ __launch_bounds__(256) void k_reduce(
    const float* __restrict__ partial, float* __restrict__ partial2, int nblk)
{
    const int gt    = blockIdx.x * 256 + threadIdx.x;  // 0..32767
    const int e     = gt & 1023;
    const int chunk = gt >> 10;                        // 0..31
    float s = 0.f;
    for (int b = chunk; b < nblk; b += NCHUNK) s += partial[(size_t)b * 1024 + e];
    partial2[chunk * 1024 + e] = s;
}

// ---------------------------------------------------------------------------
// Kernel 3: tail — gram fold (32 ILP loads) + conv2+BN+ReLU + conv3+BN+ReLU
// + mean. Branch-free convs via zero-padded LDS.
// ---------------------------------------------------------------------------
__global__ __launch_bounds__(1024) void k_tail(
    const float* __restrict__ partial2,   // [NCHUNK][1024]
    const float* __restrict__ w2, const float* __restrict__ b2,
    const float* __restrict__ g2, const float* __restrict__ bt2,
    const float* __restrict__ w3, const float* __restrict__ b3,
    const float* __restrict__ g3, const float* __restrict__ bt3,
    float* __restrict__ out)
{
    __shared__ float G_pad[36 * 36];     // zero halo 2
    __shared__ float y1[16 * 289];       // conv2 raw out (for BN stats)
    __shared__ float y1p[16 * 21 * 21];  // BN1+ReLU, zero halo 2
    __shared__ float y2[32 * 100];
    __shared__ float m1[16], r1[16];
    __shared__ float sw2[144], sp2[48];
    __shared__ float sw3[4608], sp3[96];

    const int t = threadIdx.x;

    // ---- phase 0: gram fold + zero pads + stage weights (independent) ----
    float s0 = 0.f, s1 = 0.f, s2 = 0.f, s3 = 0.f;
#pragma unroll
    for (int k = 0; k < NCHUNK; k += 4) {
        s0 += partial2[(k + 0) * 1024 + t];
        s1 += partial2[(k + 1) * 1024 + t];
        s2 += partial2[(k + 2) * 1024 + t];
        s3 += partial2[(k + 3) * 1024 + t];
    }
    const float g = (s0 + s1) + (s2 + s3);

    for (int i = t; i < 1296; i += 1024) G_pad[i] = 0.f;
    for (int i = t; i < 7056; i += 1024) y1p[i] = 0.f;
    for (int i = t; i < 144; i += 1024) sw2[i] = w2[i];
    for (int i = t; i < 4608; i += 1024) sw3[i] = w3[i];
    if (t < 16)              sp2[t]      = b2[t];
    else if (t < 32)         sp2[t]      = g2[t - 16];
    else if (t < 48)         sp2[t]      = bt2[t - 32];
    if (t >= 64 && t < 96)   sp3[t - 64] = b3[t - 64];
    else if (t >= 96 && t < 128)  sp3[t - 64] = g3[t - 96];
    else if (t >= 128 && t < 160) sp3[t - 64] = bt3[t - 128];
    __syncthreads();

    G_pad[((t >> 5) + 2) * 36 + (t & 31) + 2] = g;
    __syncthreads();

    // ---- conv2 (branch-free): 16x17x17 ----
    for (int idx = t; idx < 16 * 289; idx += 1024) {
        const int oc = idx / 289;
        const int r  = idx - oc * 289;
        const int oy = r / 17, ox = r - (r / 17) * 17;
        const float* gp = &G_pad[(2 * oy) * 36 + 2 * ox];
        const float* wr = &sw2[oc * 9];
        float s = sp2[oc];
#pragma unroll
        for (int ky = 0; ky < 3; ++ky)
#pragma unroll
            for (int kx = 0; kx < 3; ++kx)
                s = fmaf(gp[ky * 36 + kx], wr[ky * 3 + kx], s);
        y1[idx] = s;
    }
    __syncthreads();

    // ---- BN1 stats: one wave per channel ----
    {
        const int ch = t >> 6, j = t & 63;
        float s = 0.f, ss = 0.f;
        for (int i = j; i < 289; i += 64) {
            float v = y1[ch * 289 + i];
            s += v; ss += v * v;
        }
#pragma unroll
        for (int o = 32; o; o >>= 1) { s += __shfl_xor(s, o); ss += __shfl_xor(ss, o); }
        if (j == 0) {
            float m = s * (1.f / 289.f);
            float var = ss * (1.f / 289.f) - m * m;
            m1[ch] = m;
            r1[ch] = rsqrtf(var + 1e-5f);
        }
    }
    __syncthreads();

    // ---- BN1 + ReLU -> padded y1p ----
    for (int idx = t; idx < 16 * 289; idx += 1024) {
        const int oc = idx / 289;
        const int r  = idx - oc * 289;
        const int oy = r / 17, ox = r - (r / 17) * 17;
        float v = (y1[idx] - m1[oc]) * r1[oc] * sp2[16 + oc] + sp2[32 + oc];
        y1p[oc * 441 + (oy + 2) * 21 + ox + 2] = v > 0.f ? v : 0.f;
    }
    __syncthreads();

    // ---- conv3 (branch-free, ic unrolled, 4 accumulators): 32x10x10 ----
    for (int idx = t; idx < 3200; idx += 1024) {
        const int oc = idx / 100;
        const int r  = idx - oc * 100;
        const int oy = r / 10, ox = r - (r / 10) * 10;
        float a0 = sp3[oc], a1 = 0.f, a2 = 0.f, a3 = 0.f;
#pragma unroll
        for (int ic = 0; ic < 16; ++ic) {
            const float* yi = &y1p[ic * 441 + (2 * oy) * 21 + 2 * ox];
            const float* wr = &sw3[(oc * 16 + ic) * 9];
            float p0 = 0.f, p1 = 0.f, p2 = 0.f;
#pragma unroll
            for (int kx = 0; kx < 3; ++kx) {
                p0 = fmaf(yi[kx],      wr[kx],     p0);
                p1 = fmaf(yi[21 + kx], wr[3 + kx], p1);
                p2 = fmaf(yi[42 + kx], wr[6 + kx], p2);
            }
            if ((ic & 3) == 0) a0 += p0 + p1 + p2;
            else if ((ic & 3) == 1) a1 += p0 + p1 + p2;
            else if ((ic & 3) == 2) a2 += p0 + p1 + p2;
            else a3 += p0 + p1 + p2;
        }
        y2[idx] = (a0 + a1) + (a2 + a3);
    }
    __syncthreads();

    // ---- BN2 + ReLU + spatial mean: 32 lanes per channel ----
    {
        const int ch = t >> 5, j = t & 31;
        float s = 0.f, ss = 0.f;
        for (int i = j; i < 100; i += 32) {
            float v = y2[ch * 100 + i];
            s += v; ss += v * v;
        }
#pragma unroll
        for (int o = 16; o; o >>= 1) { s += __shfl_xor(s, o); ss += __shfl_xor(ss, o); }
        const float m  = s * 0.01f;
        const float var = ss * 0.01f - m * m;
        const float rs = rsqrtf(var + 1e-5f);
        float a = 0.f;
        for (int i = j; i < 100; i += 32) {
            float v = (y2[ch * 100 + i] - m) * rs * sp3[32 + ch] + sp3[64 + ch];
            a += v > 0.f ? v : 0.f;
        }
#pragma unroll
        for (int o = 16; o; o >>= 1) a += __shfl_xor(a, o);
        if (j == 0) out[ch] = a * 0.01f;
    }
}

// ---------------------------------------------------------------------------
extern "C" void kernel_launch(void* const* d_in, const int* in_sizes, int n_in,
                              void* d_out, int out_size, void* d_ws, size_t ws_size,
                              hipStream_t stream)
{
    const float* x   = (const float*)d_in[0];
    const float* w1  = (const float*)d_in[1];
    const float* b1  = (const float*)d_in[2];
    const float* w2  = (const float*)d_in[3];
    const float* b2  = (const float*)d_in[4];
    const float* g2  = (const float*)d_in[5];
    const float* bt2 = (const float*)d_in[6];
    const float* w3  = (const float*)d_in[7];
    const float* b3  = (const float*)d_in[8];
    const float* g3  = (const float*)d_in[9];
    const float* bt3 = (const float*)d_in[10];

    size_t cap = ws_size / 4096;               // 1024-float slots available
    int nblk = NBLK_MAX;
    if ((size_t)(nblk + NCHUNK) > cap) nblk = (int)cap - NCHUNK;
    if (nblk > NBLK_MAX) nblk = NBLK_MAX;
    if (nblk < 256) nblk = 256;
    nblk &= ~7;                                // banding needs nblk % 8 == 0

    float* P   = (float*)d_ws;                  // [nblk][1024]
    float* P2  = P + (size_t)nblk * 1024;       // [NCHUNK][1024]
    float* out = (float*)d_out;

    k_conv_gram<<<nblk, 256, 0, stream>>>(x, w1, b1, P, nblk);
    k_reduce<<<128, 256, 0, stream>>>(P, P2, nblk);
    k_tail<<<1, 1024, 0, stream>>>(P2, w2, b2, g2, bt2, w3, b3, g3, bt3, out);
}

// Round 11
// 64.042 us; speedup vs baseline: 6.2583x; 1.0339x over previous
//
#include <hip/hip_runtime.h>

#define NTILES_X 65          // ceil(1026/16)
#define NTILES   (65*65)     // 4225
#define OHW      1026
#define NCHUNK   32
#define NBLK_MAX 2048
#define NXCD     8
#define BAND     529         // ceil(NTILES/NXCD)

typedef unsigned int  uint;
typedef unsigned short ushort;
typedef float  floatx16 __attribute__((ext_vector_type(16)));
typedef __bf16 bf16x8   __attribute__((ext_vector_type(8)));

__device__ __forceinline__ uint pk2f(float a, float b) {
    ushort lo = __builtin_bit_cast(ushort, (__bf16)a);
    ushort hi = __builtin_bit_cast(ushort, (__bf16)b);
    return (uint)lo | ((uint)hi << 16);
}
__device__ __forceinline__ bf16x8 frag_of(uint a, uint b, uint c, uint d) {
    uint4 u = make_uint4(a, b, c, d);
    return __builtin_bit_cast(bf16x8, u);
}
// k -> element offset in sInB[3][18][18]  (k = ic*9 + ky*3 + kx)
__device__ __forceinline__ constexpr int koff_of(int k) {
    return (k / 9) * 324 + ((k % 9) / 3) * 18 + (k % 3);
}
// one patch-frag u16: slot k = (h ? kb : ka); ka,kb compile-time (kb = ka+8).
// k==27 is the bias slot (B=1.0); k>27 -> 0.
__device__ __forceinline__ uint bslot(const ushort* sInB, int base, int h, int ka, int kb) {
    if (kb < 27) {
        int off = h ? koff_of(kb) : koff_of(ka);
        return (uint)sInB[base + off];
    } else if (ka < 27) {
        uint cst = (kb == 27) ? 0x3F80u : 0u;
        uint rd  = (uint)sInB[base + koff_of(ka)];
        return h ? cst : rd;
    } else {
        uint ca = (ka == 27) ? 0x3F80u : 0u;
        uint cb2 = (kb == 27) ? 0x3F80u : 0u;
        return h ? cb2 : ca;
    }
}

// ---------------------------------------------------------------------------
// Kernel 1: conv1 via implicit-GEMM MFMA, gram fed DIRECTLY from conv D-regs.
// Conv computes D = mfma(A=patches, B=W^T) -> D[row=px][col=ch]: lane=ch,
// regs=16 px (row = m + 8q + 4h, HW-verified). pk2f reg pairs -> two bf16x8
// frags (regs 0-7 = px 0..15, regs 8-15 = px 16..31 of the col-block) which
// ARE the gram A/B frags (lane=ch ✓, k=px, any consistent bijection valid).
// No F staging in LDS at all. Border px masked per-reg (3% of tiles).
// Operand-swap safety: R6-R10 passing proves sigma_A == sigma_B.
// ---------------------------------------------------------------------------
__global__ __launch_bounds__(256, 4) void k_conv_gram(
    const float* __restrict__ x,   // [3][1024][1024]
    const float* __restrict__ w1,  // [32][3][3][3]
    const float* __restrict__ b1,  // [32]
    float* __restrict__ partial,   // [nblk][1024]
    int nblk)
{
    __shared__ __align__(16) ushort sInB[3*18*18];   // 1.9 KB bf16 input tile
    __shared__ __align__(16) float  gep[4096];       // 16 KB epilogue reduce buf

    const int t    = threadIdx.x;
    const int wv   = t >> 6;
    const int lane = t & 63;
    const int h    = lane >> 5;
    const int c    = lane & 31;        // ch for W-frag / gram row / patch px-col

    // ---- weight(+bias) fragments, built once ----
    const float b1c = b1[c];
    uint wu0[4], wu1[4];
#pragma unroll
    for (int q = 0; q < 4; ++q) {
        {
            int k0 = h * 8 + 2 * q;
            wu0[q] = pk2f(w1[c * 27 + k0], w1[c * 27 + k0 + 1]);
        }
        {
            int k0 = 16 + h * 8 + 2 * q, k1 = k0 + 1;
            float r0 = w1[c * 27 + (k0 < 27 ? k0 : 26)];
            float r1 = w1[c * 27 + (k1 < 27 ? k1 : 26)];
            float v0 = (k0 < 27) ? r0 : (k0 == 27 ? b1c : 0.f);
            float v1 = (k1 < 27) ? r1 : (k1 == 27 ? b1c : 0.f);
            wu1[q] = pk2f(v0, v1);
        }
    }

    floatx16 gacc;
#pragma unroll
    for (int i = 0; i < 16; ++i) gacc[i] = 0.f;

    // XCD band: performance-only heuristic (correct for ANY dispatch order)
    const int xcd    = blockIdx.x & (NXCD - 1);
    const int lb     = blockIdx.x >> 3;
    const int nb_per = nblk >> 3;
    const int tstart = xcd * BAND;
    const int tend   = (tstart + BAND < NTILES) ? tstart + BAND : NTILES;

    for (int tile = tstart + lb; tile < tend; tile += nb_per) {
        const int ty = tile / NTILES_X;
        const int tx = tile - ty * NTILES_X;
        const int by = ty * 16, bx = tx * 16;
        const bool interior = (ty >= 1) & (ty <= 62) & (tx >= 1) & (tx <= 62);
        const bool needmask = (ty == 64) | (tx == 64);

        __syncthreads();   // prev-tile conv reads of sInB done
        if (interior) {
            for (int i = t; i < 972; i += 256) {
                int ic = i / 324, rem = i - ic * 324, r = rem / 18, cc = rem - r * 18;
                float v = x[ic * 1048576 + (by - 2 + r) * 1024 + (bx - 2 + cc)];
                sInB[i] = __builtin_bit_cast(ushort, (__bf16)v);
            }
        } else {
            for (int i = t; i < 972; i += 256) {
                int ic = i / 324, rem = i - ic * 324, r = rem / 18, cc = rem - r * 18;
                int iy = by - 2 + r, ix = bx - 2 + cc;
                float v = 0.f;
                if ((unsigned)iy < 1024u && (unsigned)ix < 1024u)
                    v = x[ic * 1048576 + iy * 1024 + ix];
                sInB[i] = __builtin_bit_cast(ushort, (__bf16)v);
            }
        }
        __syncthreads();   // sInB ready

#pragma unroll
        for (int e = 0; e < 2; ++e) {
            const int cb   = 2 * wv + e;              // col-block: px 32cb..+31
            const int base = (cb * 2 + (c >> 4)) * 18 + (c & 15);

            floatx16 cacc;
#pragma unroll
            for (int i = 0; i < 16; ++i) cacc[i] = 0.f;

            uint bu[4];
#pragma unroll
            for (int q = 0; q < 4; ++q) {
                uint lo = bslot(sInB, base, h, 2*q,     2*q + 8);
                uint hi = bslot(sInB, base, h, 2*q + 1, 2*q + 9);
                bu[q] = lo | (hi << 16);
            }
            // A=patches, B=W^T  ->  D[row=px][col=ch]
            cacc = __builtin_amdgcn_mfma_f32_32x32x16_bf16(
                frag_of(bu[0], bu[1], bu[2], bu[3]),
                frag_of(wu0[0], wu0[1], wu0[2], wu0[3]), cacc, 0, 0, 0);
#pragma unroll
            for (int q = 0; q < 4; ++q) {
                uint lo = bslot(sInB, base, h, 16 + 2*q,     16 + 2*q + 8);
                uint hi = bslot(sInB, base, h, 16 + 2*q + 1, 16 + 2*q + 9);
                bu[q] = lo | (hi << 16);
            }
            cacc = __builtin_amdgcn_mfma_f32_32x32x16_bf16(
                frag_of(bu[0], bu[1], bu[2], bu[3]),
                frag_of(wu1[0], wu1[1], wu1[2], wu1[3]), cacc, 0, 0, 0);

            // ---- pack D regs -> two gram frags (px 0..15, px 16..31) ----
            uint pa[4], pb[4];
#pragma unroll
            for (int q2 = 0; q2 < 4; ++q2) {
                pa[q2] = pk2f(cacc[2*q2],     cacc[2*q2 + 1]);
                pb[q2] = pk2f(cacc[8 + 2*q2], cacc[8 + 2*q2 + 1]);
            }
            if (needmask) {
                const uint rA = (uint)((by + 2*cb)     < OHW);
                const uint rB = (uint)((by + 2*cb + 1) < OHW);
#pragma unroll
                for (int q2 = 0; q2 < 4; ++q2) {
                    const int q  = q2 >> 1, mm = 2 * (q2 & 1);
                    const uint x0 = (uint)((bx + 8*q + 4*h + mm)     < OHW);
                    const uint x1 = (uint)((bx + 8*q + 4*h + mm + 1) < OHW);
                    pa[q2] &= ((rA & x0) ? 0x0000FFFFu : 0u) | ((rA & x1) ? 0xFFFF0000u : 0u);
                    pb[q2] &= ((rB & x0) ? 0x0000FFFFu : 0u) | ((rB & x1) ? 0xFFFF0000u : 0u);
                }
            }
            bf16x8 fa = frag_of(pa[0], pa[1], pa[2], pa[3]);
            bf16x8 fb = frag_of(pb[0], pb[1], pb[2], pb[3]);
            gacc = __builtin_amdgcn_mfma_f32_32x32x16_bf16(fa, fa, gacc, 0, 0, 0);
            gacc = __builtin_amdgcn_mfma_f32_32x32x16_bf16(fb, fb, gacc, 0, 0, 0);
        }
    }

    // ---- epilogue: C-layout scatter, cross-wave reduce, store ----
    __syncthreads();
#pragma unroll
    for (int r = 0; r < 16; ++r) {
        const int row = (r & 3) + 8 * (r >> 2) + 4 * h;
        gep[wv * 1024 + row * 32 + c] = gacc[r];
    }
    __syncthreads();
    {
        const int e = t * 4;
        float s[4] = {0.f, 0.f, 0.f, 0.f};
#pragma unroll
        for (int w = 0; w < 4; ++w) {
            float v[4];
            *(float4*)v = *(const float4*)&gep[w * 1024 + e];
#pragma unroll
            for (int j = 0; j < 4; ++j) s[j] += v[j];
        }
        *(float4*)&partial[(size_t)blockIdx.x * 1024 + e] = *(float4*)s;
    }
}

// ---------------------------------------------------------------------------
// Kernel 2: reduce nblk partials -> NCHUNK partials. 32768 threads, coalesced.
// ---------------------------------------------------------------------------
__global__ __launch_bounds__(256) void k_reduce(
    const float* __restrict__ partial, float* __restrict__ partial2, int nblk)
{
    const int gt    = blockIdx.x * 256 + threadIdx.x;
    const int e     = gt & 1023;
    const int chunk = gt >> 10;
    float s = 0.f;
    for (int b = chunk; b < nblk; b += NCHUNK) s += partial[(size_t)b * 1024 + e];
    partial2[chunk * 1024 + e] = s;
}

// ---------------------------------------------------------------------------
// Kernel 3: tail — gram fold + conv2+BN+ReLU + conv3+BN+ReLU + mean.
// ---------------------------------------------------------------------------
__global__ __launch_bounds__(1024) void k_tail(
    const float* __restrict__ partial2,   // [NCHUNK][1024]
    const float* __restrict__ w2, const float* __restrict__ b2,
    const float* __restrict__ g2, const float* __restrict__ bt2,
    const float* __restrict__ w3, const float* __restrict__ b3,
    const float* __restrict__ g3, const float* __restrict__ bt3,
    float* __restrict__ out)
{
    __shared__ float G_pad[36 * 36];
    __shared__ float y1[16 * 289];
    __shared__ float y1p[16 * 21 * 21];
    __shared__ float y2[32 * 100];
    __shared__ float m1[16], r1[16];
    __shared__ float sw2[144], sp2[48];
    __shared__ float sw3[4608], sp3[96];

    const int t = threadIdx.x;

    float s0 = 0.f, s1 = 0.f, s2 = 0.f, s3 = 0.f;
#pragma unroll
    for (int k = 0; k < NCHUNK; k += 4) {
        s0 += partial2[(k + 0) * 1024 + t];
        s1 += partial2[(k + 1) * 1024 + t];
        s2 += partial2[(k + 2) * 1024 + t];
        s3 += partial2[(k + 3) * 1024 + t];
    }
    const float g = (s0 + s1) + (s2 + s3);

    for (int i = t; i < 1296; i += 1024) G_pad[i] = 0.f;
    for (int i = t; i < 7056; i += 1024) y1p[i] = 0.f;
    for (int i = t; i < 144; i += 1024) sw2[i] = w2[i];
    for (int i = t; i < 4608; i += 1024) sw3[i] = w3[i];
    if (t < 16)              sp2[t]      = b2[t];
    else if (t < 32)         sp2[t]      = g2[t - 16];
    else if (t < 48)         sp2[t]      = bt2[t - 32];
    if (t >= 64 && t < 96)   sp3[t - 64] = b3[t - 64];
    else if (t >= 96 && t < 128)  sp3[t - 64] = g3[t - 96];
    else if (t >= 128 && t < 160) sp3[t - 64] = bt3[t - 128];
    __syncthreads();

    G_pad[((t >> 5) + 2) * 36 + (t & 31) + 2] = g;
    __syncthreads();

    for (int idx = t; idx < 16 * 289; idx += 1024) {
        const int oc = idx / 289;
        const int r  = idx - oc * 289;
        const int oy = r / 17, ox = r - (r / 17) * 17;
        const float* gp = &G_pad[(2 * oy) * 36 + 2 * ox];
        const float* wr = &sw2[oc * 9];
        float s = sp2[oc];
#pragma unroll
        for (int ky = 0; ky < 3; ++ky)
#pragma unroll
            for (int kx = 0; kx < 3; ++kx)
                s = fmaf(gp[ky * 36 + kx], wr[ky * 3 + kx], s);
        y1[idx] = s;
    }
    __syncthreads();

    {
        const int ch = t >> 6, j = t & 63;
        float s = 0.f, ss = 0.f;
        for (int i = j; i < 289; i += 64) {
            float v = y1[ch * 289 + i];
            s += v; ss += v * v;
        }
#pragma unroll
        for (int o = 32; o; o >>= 1) { s += __shfl_xor(s, o); ss += __shfl_xor(ss, o); }
        if (j == 0) {
            float m = s * (1.f / 289.f);
            float var = ss * (1.f / 289.f) - m * m;
            m1[ch] = m;
            r1[ch] = rsqrtf(var + 1e-5f);
        }
    }
    __syncthreads();

    for (int idx = t; idx < 16 * 289; idx += 1024) {
        const int oc = idx / 289;
        const int r  = idx - oc * 289;
        const int oy = r / 17, ox = r - (r / 17) * 17;
        float v = (y1[idx] - m1[oc]) * r1[oc] * sp2[16 + oc] + sp2[32 + oc];
        y1p[oc * 441 + (oy + 2) * 21 + ox + 2] = v > 0.f ? v : 0.f;
    }
    __syncthreads();

    for (int idx = t; idx < 3200; idx += 1024) {
        const int oc = idx / 100;
        const int r  = idx - oc * 100;
        const int oy = r / 10, ox = r - (r / 10) * 10;
        float a0 = sp3[oc], a1 = 0.f, a2 = 0.f, a3 = 0.f;
#pragma unroll
        for (int ic = 0; ic < 16; ++ic) {
            const float* yi = &y1p[ic * 441 + (2 * oy) * 21 + 2 * ox];
            const float* wr = &sw3[(oc * 16 + ic) * 9];
            float p0 = 0.f, p1 = 0.f, p2 = 0.f;
#pragma unroll
            for (int kx = 0; kx < 3; ++kx) {
                p0 = fmaf(yi[kx],      wr[kx],     p0);
                p1 = fmaf(yi[21 + kx], wr[3 + kx], p1);
                p2 = fmaf(yi[42 + kx], wr[6 + kx], p2);
            }
            if ((ic & 3) == 0) a0 += p0 + p1 + p2;
            else if ((ic & 3) == 1) a1 += p0 + p1 + p2;
            else if ((ic & 3) == 2) a2 += p0 + p1 + p2;
            else a3 += p0 + p1 + p2;
        }
        y2[idx] = (a0 + a1) + (a2 + a3);
    }
    __syncthreads();

    {
        const int ch = t >> 5, j = t & 31;
        float s = 0.f, ss = 0.f;
        for (int i = j; i < 100; i += 32) {
            float v = y2[ch * 100 + i];
            s += v; ss += v * v;
        }
#pragma unroll
        for (int o = 16; o; o >>= 1) { s += __shfl_xor(s, o); ss += __shfl_xor(ss, o); }
        const float m  = s * 0.01f;
        const float var = ss * 0.01f - m * m;
        const float rs = rsqrtf(var + 1e-5f);
        float a = 0.f;
        for (int i = j; i < 100; i += 32) {
            float v = (y2[ch * 100 + i] - m) * rs * sp3[32 + ch] + sp3[64 + ch];
            a += v > 0.f ? v : 0.f;
        }
#pragma unroll
        for (int o = 16; o; o >>= 1) a += __shfl_xor(a, o);
        if (j == 0) out[ch] = a * 0.01f;
    }
}

// ---------------------------------------------------------------------------
extern "C" void kernel_launch(void* const* d_in, const int* in_sizes, int n_in,
                              void* d_out, int out_size, void* d_ws, size_t ws_size,
                              hipStream_t stream)
{
    const float* x   = (const float*)d_in[0];
    const float* w1  = (const float*)d_in[1];
    const float* b1  = (const float*)d_in[2];
    const float* w2  = (const float*)d_in[3];
    const float* b2  = (const float*)d_in[4];
    const float* g2  = (const float*)d_in[5];
    const float* bt2 = (const float*)d_in[6];
    const float* w3  = (const float*)d_in[7];
    const float* b3  = (const float*)d_in[8];
    const float* g3  = (const float*)d_in[9];
    const float* bt3 = (const float*)d_in[10];

    size_t cap = ws_size / 4096;
    int nblk = NBLK_MAX;
    if ((size_t)(nblk + NCHUNK) > cap) nblk = (int)cap - NCHUNK;
    if (nblk > NBLK_MAX) nblk = NBLK_MAX;
    if (nblk < 256) nblk = 256;
    nblk &= ~7;                                // banding needs nblk % 8 == 0

    float* P   = (float*)d_ws;                  // [nblk][1024]
    float* P2  = P + (size_t)nblk * 1024;       // [NCHUNK][1024]
    float* out = (float*)d_out;

    k_conv_gram<<<nblk, 256, 0, stream>>>(x, w1, b1, P, nblk);
    k_reduce<<<128, 256, 0, stream>>>(P, P2, nblk);
    k_tail<<<1, 1024, 0, stream>>>(P2, w2, b2, g2, bt2, w3, b3, g3, bt3, out);
}

// Round 12
// 41.581 us; speedup vs baseline: 9.6388x; 1.5402x over previous
//
#include <hip/hip_runtime.h>

#define NTILES_X 65          // ceil(1026/16)
#define NTILES   (65*65)     // 4225
#define OHW      1026
#define NCHUNK   32
#define NBLK     1024        // all co-resident (4 blocks/CU), 4-5 tiles each
#define NXCD     8
#define BAND     529         // ceil(NTILES/NXCD)

typedef unsigned int  uint;
typedef unsigned short ushort;
typedef float  floatx16 __attribute__((ext_vector_type(16)));
typedef __bf16 bf16x8   __attribute__((ext_vector_type(8)));

__device__ __forceinline__ uint pk2f(float a, float b) {
    ushort lo = __builtin_bit_cast(ushort, (__bf16)a);
    ushort hi = __builtin_bit_cast(ushort, (__bf16)b);
    return (uint)lo | ((uint)hi << 16);
}
__device__ __forceinline__ bf16x8 frag_of(uint a, uint b, uint c, uint d) {
    uint4 u = make_uint4(a, b, c, d);
    return __builtin_bit_cast(bf16x8, u);
}
// k -> element offset in a [3][18][18] tile  (k = ic*9 + ky*3 + kx)
__device__ __forceinline__ constexpr int koff_of(int k) {
    return (k / 9) * 324 + ((k % 9) / 3) * 18 + (k % 3);
}
// one patch-frag u16: slot k = (h ? kb : ka); ka,kb compile-time (kb = ka+8).
// k==27 is the bias slot (B=1.0); k>27 -> 0.
__device__ __forceinline__ uint bslot(const ushort* buf, int base, int h, int ka, int kb) {
    if (kb < 27) {
        int off = h ? koff_of(kb) : koff_of(ka);
        return (uint)buf[base + off];
    } else if (ka < 27) {
        uint cst = (kb == 27) ? 0x3F80u : 0u;
        uint rd  = (uint)buf[base + koff_of(ka)];
        return h ? cst : rd;
    } else {
        uint ca  = (ka == 27) ? 0x3F80u : 0u;
        uint cb2 = (kb == 27) ? 0x3F80u : 0u;
        return h ? cb2 : ca;
    }
}

// ---------------------------------------------------------------------------
// Kernel 1: conv1 implicit-GEMM MFMA + gram from conv D-regs (R11-proven),
// now with double-buffered LDS staging (regs->LDS, ONE barrier per tile;
// next tile's HBM loads overlap current tile's compute).
// ---------------------------------------------------------------------------
__global__ __launch_bounds__(256, 4) void k_conv_gram(
    const float* __restrict__ x,   // [3][1024][1024]
    const float* __restrict__ w1,  // [32][3][3][3]
    const float* __restrict__ b1,  // [32]
    float* __restrict__ partial,   // [NBLK][1024]
    int nblk)
{
    __shared__ __align__(16) ushort sInB[2][976];    // dbuf bf16 input tiles
    __shared__ __align__(16) float  gep[4096];       // 16 KB epilogue reduce buf

    const int t    = threadIdx.x;
    const int wv   = t >> 6;
    const int lane = t & 63;
    const int h    = lane >> 5;
    const int c    = lane & 31;

    // ---- weight(+bias) fragments, built once ----
    const float b1c = b1[c];
    uint wu0[4], wu1[4];
#pragma unroll
    for (int q = 0; q < 4; ++q) {
        {
            int k0 = h * 8 + 2 * q;
            wu0[q] = pk2f(w1[c * 27 + k0], w1[c * 27 + k0 + 1]);
        }
        {
            int k0 = 16 + h * 8 + 2 * q, k1 = k0 + 1;
            float r0 = w1[c * 27 + (k0 < 27 ? k0 : 26)];
            float r1 = w1[c * 27 + (k1 < 27 ? k1 : 26)];
            float v0 = (k0 < 27) ? r0 : (k0 == 27 ? b1c : 0.f);
            float v1 = (k1 < 27) ? r1 : (k1 == 27 ? b1c : 0.f);
            wu1[q] = pk2f(v0, v1);
        }
    }

    floatx16 gacc;
#pragma unroll
    for (int i = 0; i < 16; ++i) gacc[i] = 0.f;

    const int xcd    = blockIdx.x & (NXCD - 1);
    const int lb     = blockIdx.x >> 3;
    const int nb_per = nblk >> 3;
    const int tstart = xcd * BAND;
    const int tend   = (tstart + BAND < NTILES) ? tstart + BAND : NTILES;

    // ---- staging helpers (as lambdas over regs) ----
    auto loadregs = [&](int tile, float* v) {
        const int ty = tile / NTILES_X;
        const int tx = tile - ty * NTILES_X;
        const int by = ty * 16, bx = tx * 16;
        const bool interior = (ty >= 1) & (ty <= 62) & (tx >= 1) & (tx <= 62);
#pragma unroll
        for (int j = 0; j < 4; ++j) {
            const int i = t + 256 * j;
            if (j == 3 && i >= 972) { v[j] = 0.f; continue; }
            int ic = i / 324, rem = i - ic * 324, r = rem / 18, cc = rem - r * 18;
            if (interior) {
                v[j] = x[ic * 1048576 + (by - 2 + r) * 1024 + (bx - 2 + cc)];
            } else {
                int iy = by - 2 + r, ix = bx - 2 + cc;
                v[j] = ((unsigned)iy < 1024u && (unsigned)ix < 1024u)
                         ? x[ic * 1048576 + iy * 1024 + ix] : 0.f;
            }
        }
    };
    auto writebuf = [&](int buf, const float* v) {
#pragma unroll
        for (int j = 0; j < 4; ++j) {
            const int i = t + 256 * j;
            if (j == 3 && i >= 972) continue;
            sInB[buf][i] = __builtin_bit_cast(ushort, (__bf16)v[j]);
        }
    };

    int tile = tstart + lb;      // every block has >=4 tiles (529/128)
    int cur  = 0;
    {
        float v[4];
        loadregs(tile, v);
        writebuf(0, v);
    }
    __syncthreads();

    for (; tile < tend; ) {
        const int nxt = tile + nb_per;
        const bool hasNext = nxt < tend;
        float vn[4];
        if (hasNext) loadregs(nxt, vn);

        // ---- compute current tile from sInB[cur] ----
        {
            const int ty = tile / NTILES_X;
            const int tx = tile - ty * NTILES_X;
            const int by = ty * 16, bx = tx * 16;
            const bool needmask = (ty == 64) | (tx == 64);
            const ushort* bufp = &sInB[cur][0];

#pragma unroll
            for (int e = 0; e < 2; ++e) {
                const int cb   = 2 * wv + e;
                const int base = (cb * 2 + (c >> 4)) * 18 + (c & 15);

                floatx16 cacc;
#pragma unroll
                for (int i = 0; i < 16; ++i) cacc[i] = 0.f;

                uint bu[4];
#pragma unroll
                for (int q = 0; q < 4; ++q) {
                    uint lo = bslot(bufp, base, h, 2*q,     2*q + 8);
                    uint hi = bslot(bufp, base, h, 2*q + 1, 2*q + 9);
                    bu[q] = lo | (hi << 16);
                }
                cacc = __builtin_amdgcn_mfma_f32_32x32x16_bf16(
                    frag_of(bu[0], bu[1], bu[2], bu[3]),
                    frag_of(wu0[0], wu0[1], wu0[2], wu0[3]), cacc, 0, 0, 0);
#pragma unroll
                for (int q = 0; q < 4; ++q) {
                    uint lo = bslot(bufp, base, h, 16 + 2*q,     16 + 2*q + 8);
                    uint hi = bslot(bufp, base, h, 16 + 2*q + 1, 16 + 2*q + 9);
                    bu[q] = lo | (hi << 16);
                }
                cacc = __builtin_amdgcn_mfma_f32_32x32x16_bf16(
                    frag_of(bu[0], bu[1], bu[2], bu[3]),
                    frag_of(wu1[0], wu1[1], wu1[2], wu1[3]), cacc, 0, 0, 0);

                uint pa[4], pb[4];
#pragma unroll
                for (int q2 = 0; q2 < 4; ++q2) {
                    pa[q2] = pk2f(cacc[2*q2],     cacc[2*q2 + 1]);
                    pb[q2] = pk2f(cacc[8 + 2*q2], cacc[8 + 2*q2 + 1]);
                }
                if (needmask) {
                    const uint rA = (uint)((by + 2*cb)     < OHW);
                    const uint rB = (uint)((by + 2*cb + 1) < OHW);
#pragma unroll
                    for (int q2 = 0; q2 < 4; ++q2) {
                        const int q  = q2 >> 1, mm = 2 * (q2 & 1);
                        const uint x0 = (uint)((bx + 8*q + 4*h + mm)     < OHW);
                        const uint x1 = (uint)((bx + 8*q + 4*h + mm + 1) < OHW);
                        pa[q2] &= ((rA & x0) ? 0x0000FFFFu : 0u) | ((rA & x1) ? 0xFFFF0000u : 0u);
                        pb[q2] &= ((rB & x0) ? 0x0000FFFFu : 0u) | ((rB & x1) ? 0xFFFF0000u : 0u);
                    }
                }
                bf16x8 fa = frag_of(pa[0], pa[1], pa[2], pa[3]);
                bf16x8 fb = frag_of(pb[0], pb[1], pb[2], pb[3]);
                gacc = __builtin_amdgcn_mfma_f32_32x32x16_bf16(fa, fa, gacc, 0, 0, 0);
                gacc = __builtin_amdgcn_mfma_f32_32x32x16_bf16(fb, fb, gacc, 0, 0, 0);
            }
        }

        if (hasNext) writebuf(cur ^ 1, vn);
        __syncthreads();
        cur ^= 1;
        tile = nxt;
    }

    // ---- epilogue: C-layout scatter, cross-wave reduce, store ----
#pragma unroll
    for (int r = 0; r < 16; ++r) {
        const int row = (r & 3) + 8 * (r >> 2) + 4 * h;
        gep[wv * 1024 + row * 32 + c] = gacc[r];
    }
    __syncthreads();
    {
        const int e = t * 4;
        float s[4] = {0.f, 0.f, 0.f, 0.f};
#pragma unroll
        for (int w = 0; w < 4; ++w) {
            float v[4];
            *(float4*)v = *(const float4*)&gep[w * 1024 + e];
#pragma unroll
            for (int j = 0; j < 4; ++j) s[j] += v[j];
        }
        *(float4*)&partial[(size_t)blockIdx.x * 1024 + e] = *(float4*)s;
    }
}

// ---------------------------------------------------------------------------
// Kernel 2: reduce NBLK partials -> NCHUNK partials. 32768 threads, coalesced.
// ---------------------------------------------------------------------------
__global__ __launch_bounds__(256) void k_reduce(
    const float* __restrict__ partial, float* __restrict__ partial2, int nblk)
{
    const int gt    = blockIdx.x * 256 + threadIdx.x;
    const int e     = gt & 1023;
    const int chunk = gt >> 10;
    float s = 0.f;
    for (int b = chunk; b < nblk; b += NCHUNK) s += partial[(size_t)b * 1024 + e];
    partial2[chunk * 1024 + e] = s;
}

// ---------------------------------------------------------------------------
// Kernel 3: mid — gram fold + conv2 + BN1 + ReLU -> y1pG (padded 16x21x21).
// ---------------------------------------------------------------------------
__global__ __launch_bounds__(1024) void k_mid(
    const float* __restrict__ partial2,   // [NCHUNK][1024]
    const float* __restrict__ w2, const float* __restrict__ b2,
    const float* __restrict__ g2, const float* __restrict__ bt2,
    float* __restrict__ y1pG)             // [16*21*21]
{
    __shared__ float G_pad[36 * 36];
    __shared__ float y1[16 * 289];
    __shared__ float m1[16], r1[16];
    __shared__ float sw2[144], sp2[48];

    const int t = threadIdx.x;

    float s0 = 0.f, s1 = 0.f, s2 = 0.f, s3 = 0.f;
#pragma unroll
    for (int k = 0; k < NCHUNK; k += 4) {
        s0 += partial2[(k + 0) * 1024 + t];
        s1 += partial2[(k + 1) * 1024 + t];
        s2 += partial2[(k + 2) * 1024 + t];
        s3 += partial2[(k + 3) * 1024 + t];
    }
    const float g = (s0 + s1) + (s2 + s3);

    for (int i = t; i < 1296; i += 1024) G_pad[i] = 0.f;
    for (int i = t; i < 144; i += 1024) sw2[i] = w2[i];
    if (t < 16)              sp2[t] = b2[t];
    else if (t < 32)         sp2[t] = g2[t - 16];
    else if (t < 48)         sp2[t] = bt2[t - 32];
    __syncthreads();

    G_pad[((t >> 5) + 2) * 36 + (t & 31) + 2] = g;
    __syncthreads();

    // conv2 (branch-free): 16x17x17
    for (int idx = t; idx < 16 * 289; idx += 1024) {
        const int oc = idx / 289;
        const int r  = idx - oc * 289;
        const int oy = r / 17, ox = r - (r / 17) * 17;
        const float* gp = &G_pad[(2 * oy) * 36 + 2 * ox];
        const float* wr = &sw2[oc * 9];
        float s = sp2[oc];
#pragma unroll
        for (int ky = 0; ky < 3; ++ky)
#pragma unroll
            for (int kx = 0; kx < 3; ++kx)
                s = fmaf(gp[ky * 36 + kx], wr[ky * 3 + kx], s);
        y1[idx] = s;
    }
    __syncthreads();

    // BN1 stats: one wave per channel
    {
        const int ch = t >> 6, j = t & 63;
        float s = 0.f, ss = 0.f;
        for (int i = j; i < 289; i += 64) {
            float v = y1[ch * 289 + i];
            s += v; ss += v * v;
        }
#pragma unroll
        for (int o = 32; o; o >>= 1) { s += __shfl_xor(s, o); ss += __shfl_xor(ss, o); }
        if (j == 0) {
            float m = s * (1.f / 289.f);
            float var = ss * (1.f / 289.f) - m * m;
            m1[ch] = m;
            r1[ch] = rsqrtf(var + 1e-5f);
        }
    }
    __syncthreads();

    // BN1 + ReLU -> padded global y1pG (halo zeros written explicitly)
    for (int idx = t; idx < 16 * 441; idx += 1024) {
        const int ic  = idx / 441;
        const int rem = idx - ic * 441;
        const int yy  = rem / 21, xx = rem - yy * 21;
        float v = 0.f;
        if (yy >= 2 && yy < 19 && xx >= 2 && xx < 19) {
            float raw = y1[ic * 289 + (yy - 2) * 17 + (xx - 2)];
            v = (raw - m1[ic]) * r1[ic] * sp2[16 + ic] + sp2[32 + ic];
            v = v > 0.f ? v : 0.f;
        }
        y1pG[idx] = v;
    }
}

// ---------------------------------------------------------------------------
// Kernel 4: c3 — one block per output channel: conv3 + BN2 + ReLU + mean.
// Weights are block-uniform -> scalar loads; 460K MACs spread over 32 CUs.
// ---------------------------------------------------------------------------
__global__ __launch_bounds__(256) void k_c3(
    const float* __restrict__ y1pG,       // [16*21*21]
    const float* __restrict__ w3, const float* __restrict__ b3,
    const float* __restrict__ g3, const float* __restrict__ bt3,
    float* __restrict__ out)              // [32]
{
    __shared__ float yL[16 * 441];        // 28.2 KB
    __shared__ float y2L[128];

    const int t  = threadIdx.x;
    const int oc = blockIdx.x;

    for (int i = t; i < 7056; i += 256) yL[i] = y1pG[i];
    if (t >= 100 && t < 128) y2L[t] = 0.f;
    __syncthreads();

    if (t < 100) {
        const int oy = t / 10, ox = t - 10 * (t / 10);
        const float* wr = w3 + oc * 144;          // block-uniform -> s_load
        float a0 = b3[oc], a1 = 0.f, a2 = 0.f;
#pragma unroll
        for (int ic = 0; ic < 16; ++ic) {
            const float* yi = &yL[ic * 441 + (2 * oy) * 21 + 2 * ox];
            const float* wi = wr + ic * 9;
#pragma unroll
            for (int kx = 0; kx < 3; ++kx) {
                a0 = fmaf(yi[kx],      wi[kx],     a0);
                a1 = fmaf(yi[21 + kx], wi[3 + kx], a1);
                a2 = fmaf(yi[42 + kx], wi[6 + kx], a2);
            }
        }
        y2L[t] = (a0 + a1) + a2;
    }
    __syncthreads();

    if (t < 64) {
        const float x0 = y2L[t], x1 = y2L[t + 64];   // slots >=100 are 0
        float s = x0 + x1, ss = x0 * x0 + x1 * x1;
#pragma unroll
        for (int o = 32; o; o >>= 1) { s += __shfl_xor(s, o); ss += __shfl_xor(ss, o); }
        const float m  = s * 0.01f;
        const float var = ss * 0.01f - m * m;
        const float rs = rsqrtf(var + 1e-5f);
        const float gg = g3[oc], bb = bt3[oc];
        float a = 0.f;
        if (t < 100) { float f = (x0 - m) * rs * gg + bb; a += f > 0.f ? f : 0.f; }
        if (t < 36)  { float f = (x1 - m) * rs * gg + bb; a += f > 0.f ? f : 0.f; }
#pragma unroll
        for (int o = 32; o; o >>= 1) a += __shfl_xor(a, o);
        if (t == 0) out[oc] = a * 0.01f;
    }
}

// ---------------------------------------------------------------------------
extern "C" void kernel_launch(void* const* d_in, const int* in_sizes, int n_in,
                              void* d_out, int out_size, void* d_ws, size_t ws_size,
                              hipStream_t stream)
{
    const float* x   = (const float*)d_in[0];
    const float* w1  = (const float*)d_in[1];
    const float* b1  = (const float*)d_in[2];
    const float* w2  = (const float*)d_in[3];
    const float* b2  = (const float*)d_in[4];
    const float* g2  = (const float*)d_in[5];
    const float* bt2 = (const float*)d_in[6];
    const float* w3  = (const float*)d_in[7];
    const float* b3  = (const float*)d_in[8];
    const float* g3  = (const float*)d_in[9];
    const float* bt3 = (const float*)d_in[10];

    int nblk = NBLK;   // 4.3 MB partials; R8 ran 8.5 MB in this ws fine

    float* P    = (float*)d_ws;                  // [NBLK][1024]
    float* P2   = P + (size_t)nblk * 1024;       // [NCHUNK][1024]
    float* y1pG = P2 + (size_t)NCHUNK * 1024;    // [7056]
    float* out  = (float*)d_out;

    k_conv_gram<<<nblk, 256, 0, stream>>>(x, w1, b1, P, nblk);
    k_reduce<<<128, 256, 0, stream>>>(P, P2, nblk);
    k_mid<<<1, 1024, 0, stream>>>(P2, w2, b2, g2, bt2, y1pG);
    k_c3<<<32, 256, 0, stream>>>(y1pG, w3, b3, g3, bt3, out);
}

// Round 13
// 39.393 us; speedup vs baseline: 10.1741x; 1.0555x over previous
//
#include <hip/hip_runtime.h>

#define NTILES_X 65          // ceil(1026/16)
#define NTILES   (65*65)     // 4225
#define OHW      1026
#define NCHUNK   32
#define NBLK     1024        // all co-resident (4 blocks/CU), 4-5 tiles each
#define NXCD     8
#define BAND     529         // ceil(NTILES/NXCD)

typedef unsigned int  uint;
typedef unsigned short ushort;
typedef float  floatx16 __attribute__((ext_vector_type(16)));
typedef __bf16 bf16x8   __attribute__((ext_vector_type(8)));

__device__ __forceinline__ uint pk2f(float a, float b) {
    ushort lo = __builtin_bit_cast(ushort, (__bf16)a);
    ushort hi = __builtin_bit_cast(ushort, (__bf16)b);
    return (uint)lo | ((uint)hi << 16);
}
__device__ __forceinline__ bf16x8 frag_of(uint a, uint b, uint c, uint d) {
    uint4 u = make_uint4(a, b, c, d);
    return __builtin_bit_cast(bf16x8, u);
}
// k -> element offset in a [3][18][18] tile  (k = ic*9 + ky*3 + kx)
__device__ __forceinline__ constexpr int koff_of(int k) {
    return (k / 9) * 324 + ((k % 9) / 3) * 18 + (k % 3);
}
// one patch-frag u16: slot k = (h ? kb : ka); ka,kb compile-time (kb = ka+8).
// k==27 is the bias slot (B=1.0); k>27 -> 0.
__device__ __forceinline__ uint bslot(const ushort* buf, int base, int h, int ka, int kb) {
    if (kb < 27) {
        int off = h ? koff_of(kb) : koff_of(ka);
        return (uint)buf[base + off];
    } else if (ka < 27) {
        uint cst = (kb == 27) ? 0x3F80u : 0u;
        uint rd  = (uint)buf[base + koff_of(ka)];
        return h ? cst : rd;
    } else {
        uint ca  = (ka == 27) ? 0x3F80u : 0u;
        uint cb2 = (kb == 27) ? 0x3F80u : 0u;
        return h ? cb2 : ca;
    }
}

// ---------------------------------------------------------------------------
// Kernel 1: conv1 implicit-GEMM MFMA + gram from conv D-regs, double-buffered
// LDS staging (R12-proven, unchanged).
// ---------------------------------------------------------------------------
__global__ __launch_bounds__(256, 4) void k_conv_gram(
    const float* __restrict__ x,   // [3][1024][1024]
    const float* __restrict__ w1,  // [32][3][3][3]
    const float* __restrict__ b1,  // [32]
    float* __restrict__ partial,   // [NBLK][1024]
    int nblk)
{
    __shared__ __align__(16) ushort sInB[2][976];    // dbuf bf16 input tiles
    __shared__ __align__(16) float  gep[4096];       // 16 KB epilogue reduce buf

    const int t    = threadIdx.x;
    const int wv   = t >> 6;
    const int lane = t & 63;
    const int h    = lane >> 5;
    const int c    = lane & 31;

    // ---- weight(+bias) fragments, built once ----
    const float b1c = b1[c];
    uint wu0[4], wu1[4];
#pragma unroll
    for (int q = 0; q < 4; ++q) {
        {
            int k0 = h * 8 + 2 * q;
            wu0[q] = pk2f(w1[c * 27 + k0], w1[c * 27 + k0 + 1]);
        }
        {
            int k0 = 16 + h * 8 + 2 * q, k1 = k0 + 1;
            float r0 = w1[c * 27 + (k0 < 27 ? k0 : 26)];
            float r1 = w1[c * 27 + (k1 < 27 ? k1 : 26)];
            float v0 = (k0 < 27) ? r0 : (k0 == 27 ? b1c : 0.f);
            float v1 = (k1 < 27) ? r1 : (k1 == 27 ? b1c : 0.f);
            wu1[q] = pk2f(v0, v1);
        }
    }

    floatx16 gacc;
#pragma unroll
    for (int i = 0; i < 16; ++i) gacc[i] = 0.f;

    const int xcd    = blockIdx.x & (NXCD - 1);
    const int lb     = blockIdx.x >> 3;
    const int nb_per = nblk >> 3;
    const int tstart = xcd * BAND;
    const int tend   = (tstart + BAND < NTILES) ? tstart + BAND : NTILES;

    auto loadregs = [&](int tile, float* v) {
        const int ty = tile / NTILES_X;
        const int tx = tile - ty * NTILES_X;
        const int by = ty * 16, bx = tx * 16;
        const bool interior = (ty >= 1) & (ty <= 62) & (tx >= 1) & (tx <= 62);
#pragma unroll
        for (int j = 0; j < 4; ++j) {
            const int i = t + 256 * j;
            if (j == 3 && i >= 972) { v[j] = 0.f; continue; }
            int ic = i / 324, rem = i - ic * 324, r = rem / 18, cc = rem - r * 18;
            if (interior) {
                v[j] = x[ic * 1048576 + (by - 2 + r) * 1024 + (bx - 2 + cc)];
            } else {
                int iy = by - 2 + r, ix = bx - 2 + cc;
                v[j] = ((unsigned)iy < 1024u && (unsigned)ix < 1024u)
                         ? x[ic * 1048576 + iy * 1024 + ix] : 0.f;
            }
        }
    };
    auto writebuf = [&](int buf, const float* v) {
#pragma unroll
        for (int j = 0; j < 4; ++j) {
            const int i = t + 256 * j;
            if (j == 3 && i >= 972) continue;
            sInB[buf][i] = __builtin_bit_cast(ushort, (__bf16)v[j]);
        }
    };

    int tile = tstart + lb;
    int cur  = 0;
    {
        float v[4];
        loadregs(tile, v);
        writebuf(0, v);
    }
    __syncthreads();

    for (; tile < tend; ) {
        const int nxt = tile + nb_per;
        const bool hasNext = nxt < tend;
        float vn[4];
        if (hasNext) loadregs(nxt, vn);

        {
            const int ty = tile / NTILES_X;
            const int tx = tile - ty * NTILES_X;
            const int by = ty * 16, bx = tx * 16;
            const bool needmask = (ty == 64) | (tx == 64);
            const ushort* bufp = &sInB[cur][0];

#pragma unroll
            for (int e = 0; e < 2; ++e) {
                const int cb   = 2 * wv + e;
                const int base = (cb * 2 + (c >> 4)) * 18 + (c & 15);

                floatx16 cacc;
#pragma unroll
                for (int i = 0; i < 16; ++i) cacc[i] = 0.f;

                uint bu[4];
#pragma unroll
                for (int q = 0; q < 4; ++q) {
                    uint lo = bslot(bufp, base, h, 2*q,     2*q + 8);
                    uint hi = bslot(bufp, base, h, 2*q + 1, 2*q + 9);
                    bu[q] = lo | (hi << 16);
                }
                cacc = __builtin_amdgcn_mfma_f32_32x32x16_bf16(
                    frag_of(bu[0], bu[1], bu[2], bu[3]),
                    frag_of(wu0[0], wu0[1], wu0[2], wu0[3]), cacc, 0, 0, 0);
#pragma unroll
                for (int q = 0; q < 4; ++q) {
                    uint lo = bslot(bufp, base, h, 16 + 2*q,     16 + 2*q + 8);
                    uint hi = bslot(bufp, base, h, 16 + 2*q + 1, 16 + 2*q + 9);
                    bu[q] = lo | (hi << 16);
                }
                cacc = __builtin_amdgcn_mfma_f32_32x32x16_bf16(
                    frag_of(bu[0], bu[1], bu[2], bu[3]),
                    frag_of(wu1[0], wu1[1], wu1[2], wu1[3]), cacc, 0, 0, 0);

                uint pa[4], pb[4];
#pragma unroll
                for (int q2 = 0; q2 < 4; ++q2) {
                    pa[q2] = pk2f(cacc[2*q2],     cacc[2*q2 + 1]);
                    pb[q2] = pk2f(cacc[8 + 2*q2], cacc[8 + 2*q2 + 1]);
                }
                if (needmask) {
                    const uint rA = (uint)((by + 2*cb)     < OHW);
                    const uint rB = (uint)((by + 2*cb + 1) < OHW);
#pragma unroll
                    for (int q2 = 0; q2 < 4; ++q2) {
                        const int q  = q2 >> 1, mm = 2 * (q2 & 1);
                        const uint x0 = (uint)((bx + 8*q + 4*h + mm)     < OHW);
                        const uint x1 = (uint)((bx + 8*q + 4*h + mm + 1) < OHW);
                        pa[q2] &= ((rA & x0) ? 0x0000FFFFu : 0u) | ((rA & x1) ? 0xFFFF0000u : 0u);
                        pb[q2] &= ((rB & x0) ? 0x0000FFFFu : 0u) | ((rB & x1) ? 0xFFFF0000u : 0u);
                    }
                }
                bf16x8 fa = frag_of(pa[0], pa[1], pa[2], pa[3]);
                bf16x8 fb = frag_of(pb[0], pb[1], pb[2], pb[3]);
                gacc = __builtin_amdgcn_mfma_f32_32x32x16_bf16(fa, fa, gacc, 0, 0, 0);
                gacc = __builtin_amdgcn_mfma_f32_32x32x16_bf16(fb, fb, gacc, 0, 0, 0);
            }
        }

        if (hasNext) writebuf(cur ^ 1, vn);
        __syncthreads();
        cur ^= 1;
        tile = nxt;
    }

    // ---- epilogue: C-layout scatter, cross-wave reduce, store ----
#pragma unroll
    for (int r = 0; r < 16; ++r) {
        const int row = (r & 3) + 8 * (r >> 2) + 4 * h;
        gep[wv * 1024 + row * 32 + c] = gacc[r];
    }
    __syncthreads();
    {
        const int e = t * 4;
        float s[4] = {0.f, 0.f, 0.f, 0.f};
#pragma unroll
        for (int w = 0; w < 4; ++w) {
            float v[4];
            *(float4*)v = *(const float4*)&gep[w * 1024 + e];
#pragma unroll
            for (int j = 0; j < 4; ++j) s[j] += v[j];
        }
        *(float4*)&partial[(size_t)blockIdx.x * 1024 + e] = *(float4*)s;
    }
}

// ---------------------------------------------------------------------------
// Kernel 2: reduce NBLK partials -> NCHUNK partials. 32768 threads, coalesced.
// ---------------------------------------------------------------------------
__global__ __launch_bounds__(256) void k_reduce(
    const float* __restrict__ partial, float* __restrict__ partial2, int nblk)
{
    const int gt    = blockIdx.x * 256 + threadIdx.x;
    const int e     = gt & 1023;
    const int chunk = gt >> 10;
    float s = 0.f;
    for (int b = chunk; b < nblk; b += NCHUNK) s += partial[(size_t)b * 1024 + e];
    partial2[chunk * 1024 + e] = s;
}

// ---------------------------------------------------------------------------
// Kernel 3: fused tail — 32 blocks (one per conv3 output channel). Every
// block REDUNDANTLY computes the cheap mid phase (P2 fold, conv2, BN1, y1p
// in LDS — ~3 us, parallel across CUs), then its own channel's conv3 (2-way
// ic split) + BN2 + ReLU + mean. Replaces k_mid->gap->k_c3 + HBM round-trip.
// ---------------------------------------------------------------------------
__global__ __launch_bounds__(256) void k_tail2(
    const float* __restrict__ partial2,   // [NCHUNK][1024]
    const float* __restrict__ w2, const float* __restrict__ b2,
    const float* __restrict__ g2, const float* __restrict__ bt2,
    const float* __restrict__ w3, const float* __restrict__ b3,
    const float* __restrict__ g3, const float* __restrict__ bt3,
    float* __restrict__ out)              // [32]
{
    __shared__ float G_pad[36 * 36];      // zero halo 2
    __shared__ float y1[16 * 289];
    __shared__ float y1p[16 * 21 * 21];   // BN1+ReLU, zero halo 2
    __shared__ float y2L[256];
    __shared__ float m1[16], r1[16];
    __shared__ float sw2[144], sp2[48];

    const int t  = threadIdx.x;
    const int oc = blockIdx.x;

    // ---- fold P2 -> g (4 elems/thread, float4 x 32 chunks) ----
    float gv[4] = {0.f, 0.f, 0.f, 0.f};
#pragma unroll
    for (int k = 0; k < NCHUNK; ++k) {
        float v[4];
        *(float4*)v = *(const float4*)&partial2[k * 1024 + t * 4];
#pragma unroll
        for (int j = 0; j < 4; ++j) gv[j] += v[j];
    }

    for (int i = t; i < 1296; i += 256) G_pad[i] = 0.f;
    for (int i = t; i < 7056; i += 256) y1p[i] = 0.f;
    if (t < 144) sw2[t] = w2[t];
    if (t >= 160 && t < 176)      sp2[t - 160]      = b2[t - 160];
    else if (t >= 176 && t < 192) sp2[t - 160]      = g2[t - 176];
    else if (t >= 192 && t < 208) sp2[t - 160]      = bt2[t - 192];
    __syncthreads();

    // G into padded LDS: element e = 4t+j at (row e>>5, col e&31)
#pragma unroll
    for (int j = 0; j < 4; ++j) {
        const int e = t * 4 + j;
        G_pad[((e >> 5) + 2) * 36 + (e & 31) + 2] = gv[j];
    }
    __syncthreads();

    // ---- conv2 (branch-free): 16x17x17 ----
    for (int idx = t; idx < 16 * 289; idx += 256) {
        const int c2 = idx / 289;
        const int r  = idx - c2 * 289;
        const int oy = r / 17, ox = r - (r / 17) * 17;
        const float* gp = &G_pad[(2 * oy) * 36 + 2 * ox];
        const float* wr = &sw2[c2 * 9];
        float s = sp2[c2];
#pragma unroll
        for (int ky = 0; ky < 3; ++ky)
#pragma unroll
            for (int kx = 0; kx < 3; ++kx)
                s = fmaf(gp[ky * 36 + kx], wr[ky * 3 + kx], s);
        y1[idx] = s;
    }
    __syncthreads();

    // ---- BN1 stats: 4 channels/wave, 16 lanes each ----
    {
        const int lane = t & 63;
        const int ch   = (t >> 6) * 4 + (lane >> 4);
        const int j    = lane & 15;
        float s = 0.f, ss = 0.f;
        for (int i = j; i < 289; i += 16) {
            float v = y1[ch * 289 + i];
            s += v; ss += v * v;
        }
#pragma unroll
        for (int o = 8; o; o >>= 1) { s += __shfl_xor(s, o); ss += __shfl_xor(ss, o); }
        if (j == 0) {
            float m = s * (1.f / 289.f);
            float var = ss * (1.f / 289.f) - m * m;
            m1[ch] = m;
            r1[ch] = rsqrtf(var + 1e-5f);
        }
    }
    __syncthreads();

    // ---- BN1 + ReLU -> padded y1p ----
    for (int idx = t; idx < 16 * 289; idx += 256) {
        const int c2 = idx / 289;
        const int r  = idx - c2 * 289;
        const int oy = r / 17, ox = r - (r / 17) * 17;
        float v = (y1[idx] - m1[c2]) * r1[c2] * sp2[16 + c2] + sp2[32 + c2];
        y1p[c2 * 441 + (oy + 2) * 21 + ox + 2] = v > 0.f ? v : 0.f;
    }
    if (t >= 100 && t < 128) y2L[t] = 0.f;     // pad for the 64-lane reduce
    __syncthreads();

    // ---- conv3 for channel oc, 2-way ic split ----
    // group A: t in [0,100)   -> px = t,      ic 0..7
    // group B: t in [128,228) -> px = t-128,  ic 8..15
    {
        const int grp = t >> 7;                // 0 or 1
        const int px  = t & 127;
        if (px < 100) {
            const int oy = px / 10, ox = px - 10 * (px / 10);
            const float* wr = w3 + oc * 144 + grp * 72;   // block-uniform
            float a0 = 0.f, a1 = 0.f, a2 = 0.f;
#pragma unroll
            for (int ic8 = 0; ic8 < 8; ++ic8) {
                const int ic = grp * 8 + ic8;
                const float* yi = &y1p[ic * 441 + (2 * oy) * 21 + 2 * ox];
                const float* wi = wr + ic8 * 9;
#pragma unroll
                for (int kx = 0; kx < 3; ++kx) {
                    a0 = fmaf(yi[kx],      wi[kx],     a0);
                    a1 = fmaf(yi[21 + kx], wi[3 + kx], a1);
                    a2 = fmaf(yi[42 + kx], wi[6 + kx], a2);
                }
            }
            y2L[grp * 128 + px] = (a0 + a1) + a2;
        }
    }
    __syncthreads();

    // combine halves + bias (t<100), then zero-padded slots stay 0
    if (t < 100) y2L[t] = y2L[t] + y2L[128 + t] + b3[oc];
    __syncthreads();

    // ---- BN2 + ReLU + mean over 100 values (slots 100..127 are 0) ----
    if (t < 64) {
        const float x0 = y2L[t], x1 = y2L[t + 64];
        float s = x0 + x1, ss = x0 * x0 + x1 * x1;
#pragma unroll
        for (int o = 32; o; o >>= 1) { s += __shfl_xor(s, o); ss += __shfl_xor(ss, o); }
        const float m   = s * 0.01f;
        const float var = ss * 0.01f - m * m;
        const float rs  = rsqrtf(var + 1e-5f);
        const float gg  = g3[oc], bb = bt3[oc];
        float a = 0.f;
        if (t < 100) { float f = (x0 - m) * rs * gg + bb; a += f > 0.f ? f : 0.f; }
        if (t < 36)  { float f = (x1 - m) * rs * gg + bb; a += f > 0.f ? f : 0.f; }
#pragma unroll
        for (int o = 32; o; o >>= 1) a += __shfl_xor(a, o);
        if (t == 0) out[oc] = a * 0.01f;
    }
}

// ---------------------------------------------------------------------------
extern "C" void kernel_launch(void* const* d_in, const int* in_sizes, int n_in,
                              void* d_out, int out_size, void* d_ws, size_t ws_size,
                              hipStream_t stream)
{
    const float* x   = (const float*)d_in[0];
    const float* w1  = (const float*)d_in[1];
    const float* b1  = (const float*)d_in[2];
    const float* w2  = (const float*)d_in[3];
    const float* b2  = (const float*)d_in[4];
    const float* g2  = (const float*)d_in[5];
    const float* bt2 = (const float*)d_in[6];
    const float* w3  = (const float*)d_in[7];
    const float* b3  = (const float*)d_in[8];
    const float* g3  = (const float*)d_in[9];
    const float* bt3 = (const float*)d_in[10];

    int nblk = NBLK;

    float* P   = (float*)d_ws;                  // [NBLK][1024]
    float* P2  = P + (size_t)nblk * 1024;       // [NCHUNK][1024]
    float* out = (float*)d_out;

    k_conv_gram<<<nblk, 256, 0, stream>>>(x, w1, b1, P, nblk);
    k_reduce<<<128, 256, 0, stream>>>(P, P2, nblk);
    k_tail2<<<32, 256, 0, stream>>>(P2, w2, b2, g2, bt2, w3, b3, g3, bt3, out);
}